// Round 3
// baseline (2388.686 us; speedup 1.0000x reference)
//
#include <hip/hip_runtime.h>
#include <cfloat>
#include <cstdint>
#include <cstddef>

#define NROWS 8192
#define HID 256
#define NCLS 5
#define TOPK 10
#define CAND 16     // merged candidates refined exactly
#define CT 16       // per-tile candidates
#define KP 512      // packed K = 2*HID (hi|lo limbs)
#define TM 128
#define TN 128
#define BK 32
#define NTILE (NROWS / TN)   // 64 col-tiles per row

typedef __bf16 bf16x8 __attribute__((ext_vector_type(8)));
typedef float f32x4 __attribute__((ext_vector_type(4)));

__device__ inline ushort f2bf(float x) {
  unsigned u = __float_as_uint(x);
  unsigned r = (u + 0x7fffu + ((u >> 16) & 1u)) >> 16;  // RNE
  return (ushort)r;
}
__device__ inline float bf2f(ushort b) { return __uint_as_float(((unsigned)b) << 16); }

// ---------------------------------------------------------------------------
// Generic tiled fp32 GEMM (encoder + GCN weight GEMMs): C = act(A@B + bias)
// ---------------------------------------------------------------------------
template<bool BIAS, int ACT>
__global__ __launch_bounds__(256) void gemm_kernel(const float* __restrict__ A,
    const float* __restrict__ B, const float* __restrict__ bias,
    float* __restrict__ C, int M, int N, int K) {
  __shared__ float As[16][68];
  __shared__ float Bs[16][68];
  const int tid = threadIdx.x;
  const int tx = tid & 15, ty = tid >> 4;
  const int bm = blockIdx.y * 64, bn = blockIdx.x * 64;
  float acc[4][4] = {};
  for (int k0 = 0; k0 < K; k0 += 16) {
    {
      const int m = tid >> 2;
      const int kq = (tid & 3) * 4;
      const int gm = bm + m, gk = k0 + kq;
      float a0 = 0.f, a1 = 0.f, a2 = 0.f, a3 = 0.f;
      if (gm < M) {
        const float* p = A + (size_t)gm * K + gk;
        if (gk + 3 < K) {
          float4 v4 = *(const float4*)p;
          a0 = v4.x; a1 = v4.y; a2 = v4.z; a3 = v4.w;
        } else {
          if (gk + 0 < K) a0 = p[0];
          if (gk + 1 < K) a1 = p[1];
          if (gk + 2 < K) a2 = p[2];
        }
      }
      As[kq + 0][m] = a0; As[kq + 1][m] = a1; As[kq + 2][m] = a2; As[kq + 3][m] = a3;
    }
    {
      const int k = tid >> 4;
      const int nq = (tid & 15) * 4;
      const int gk = k0 + k, gn = bn + nq;
      float b0 = 0.f, b1 = 0.f, b2 = 0.f, b3 = 0.f;
      if (gk < K) {
        const float* p = B + (size_t)gk * N + gn;
        if (gn + 3 < N) {
          float4 v4 = *(const float4*)p;
          b0 = v4.x; b1 = v4.y; b2 = v4.z; b3 = v4.w;
        } else {
          if (gn + 0 < N) b0 = p[0];
          if (gn + 1 < N) b1 = p[1];
          if (gn + 2 < N) b2 = p[2];
        }
      }
      Bs[k][nq + 0] = b0; Bs[k][nq + 1] = b1; Bs[k][nq + 2] = b2; Bs[k][nq + 3] = b3;
    }
    __syncthreads();
    #pragma unroll
    for (int kk = 0; kk < 16; ++kk) {
      float a0 = As[kk][ty * 4 + 0], a1 = As[kk][ty * 4 + 1];
      float a2 = As[kk][ty * 4 + 2], a3 = As[kk][ty * 4 + 3];
      float b0 = Bs[kk][tx * 4 + 0], b1 = Bs[kk][tx * 4 + 1];
      float b2 = Bs[kk][tx * 4 + 2], b3 = Bs[kk][tx * 4 + 3];
      acc[0][0] += a0 * b0; acc[0][1] += a0 * b1; acc[0][2] += a0 * b2; acc[0][3] += a0 * b3;
      acc[1][0] += a1 * b0; acc[1][1] += a1 * b1; acc[1][2] += a1 * b2; acc[1][3] += a1 * b3;
      acc[2][0] += a2 * b0; acc[2][1] += a2 * b1; acc[2][2] += a2 * b2; acc[2][3] += a2 * b3;
      acc[3][0] += a3 * b0; acc[3][1] += a3 * b1; acc[3][2] += a3 * b2; acc[3][3] += a3 * b3;
    }
    __syncthreads();
  }
  #pragma unroll
  for (int i = 0; i < 4; ++i) {
    const int gm = bm + ty * 4 + i;
    if (gm >= M) continue;
    #pragma unroll
    for (int jj = 0; jj < 4; ++jj) {
      const int gn = bn + tx * 4 + jj;
      if (gn >= N) continue;
      float v = acc[i][jj];
      if (BIAS) v += bias[gn];
      if (ACT == 1) v = fmaxf(v, 0.f);
      C[(size_t)gm * N + gn] = v;
    }
  }
}

// ---------------------------------------------------------------------------
// BatchNorm1d (training stats, biased var, eps=1e-5), in place.
// ---------------------------------------------------------------------------
__global__ __launch_bounds__(256) void bn_kernel(float* __restrict__ F,
    const float* __restrict__ g, const float* __restrict__ b) {
  const int j = blockIdx.x, t = threadIdx.x;
  float s = 0.f, s2 = 0.f;
  for (int r = t; r < NROWS; r += 256) {
    float v = F[(size_t)r * HID + j];
    s += v; s2 += v * v;
  }
  __shared__ float sh1[256];
  __shared__ float sh2[256];
  sh1[t] = s; sh2[t] = s2;
  __syncthreads();
  for (int st = 128; st > 0; st >>= 1) {
    if (t < st) { sh1[t] += sh1[t + st]; sh2[t] += sh2[t + st]; }
    __syncthreads();
  }
  const float mu = sh1[0] / (float)NROWS;
  const float var = sh2[0] / (float)NROWS - mu * mu;
  const float rstd = rsqrtf(var + 1e-5f);
  const float gg = g[j], bb = b[j];
  for (int r = t; r < NROWS; r += 256) {
    const size_t o = (size_t)r * HID + j;
    F[o] = (F[o] - mu) * rstd * gg + bb;
  }
}

// ---------------------------------------------------------------------------
// L2 row-normalize fn = feat/||feat||.
// ---------------------------------------------------------------------------
__global__ __launch_bounds__(256) void rownorm_kernel(const float* __restrict__ F,
    float* __restrict__ FN) {
  const int r = blockIdx.x, t = threadIdx.x;
  const float v = F[(size_t)r * HID + t];
  __shared__ float sh[256];
  sh[t] = v * v;
  __syncthreads();
  for (int st = 128; st > 0; st >>= 1) {
    if (t < st) sh[t] += sh[t + st];
    __syncthreads();
  }
  const float inv = 1.0f / fmaxf(sqrtf(sh[0]), 1e-12f);
  FN[(size_t)r * HID + t] = v * inv;
}

// ---------------------------------------------------------------------------
// Pack fn into two-limb bf16: P[r] = [bf16(x) | bf16(x - hi)], K = 512.
// ---------------------------------------------------------------------------
__global__ __launch_bounds__(256) void pack_kernel(const float* __restrict__ FN,
    ushort* __restrict__ P) {
  const int id = blockIdx.x * 256 + threadIdx.x;
  const int r = id >> 8, k = id & 255;
  const float x = FN[id];
  const ushort h = f2bf(x);
  const ushort l = f2bf(x - bf2f(h));
  P[(size_t)r * KP + k] = h;
  P[(size_t)r * KP + HID + k] = l;
}

// ---------------------------------------------------------------------------
// Fused sim-tile MFMA + per-tile top-16.
// 128x128 tile of sim = P @ P^T (K=512, two-limb bf16). C fragments are
// dumped into a transposed padded LDS tile (conflict-free column scans),
// then 128 threads extract a sorted per-row top-16 (self-masked) and write
// (value, global col) candidate lists. Sim never touches HBM.
// LDS: staging (16 KB) and tile (66 KB) share one union -> 2 blocks/CU.
// ---------------------------------------------------------------------------
struct SimLds {
  union {
    struct { ushort As[TM * BK]; ushort Bs[TN * BK]; } st;
    float tileT[TN][TM + 1];
  };
};

__global__ __launch_bounds__(256) void simtopk_kernel(const ushort* __restrict__ P,
    float* __restrict__ cval, int* __restrict__ cidx) {
  __shared__ SimLds u;
  const int tid = threadIdx.x;
  const int wave = tid >> 6, lane = tid & 63;
  const int bm = blockIdx.y * TM;
  const int bn = blockIdx.x * TN;
  const int wr = (wave >> 1) * 64;
  const int wc = (wave & 1) * 64;

  f32x4 acc[4][4];
  const f32x4 zero = {0.f, 0.f, 0.f, 0.f};
  #pragma unroll
  for (int i = 0; i < 4; ++i)
    #pragma unroll
    for (int j = 0; j < 4; ++j) acc[i][j] = zero;

  const int p0 = tid, p1 = tid + 256;
  const int r0 = p0 >> 2, kl0 = (p0 & 3) ^ ((r0 & 3) ^ ((r0 >> 2) & 1));
  const int r1 = p1 >> 2, kl1 = (p1 & 3) ^ ((r1 & 3) ^ ((r1 >> 2) & 1));
  const ushort* pa0 = P + (size_t)(bm + r0) * KP + kl0 * 8;
  const ushort* pa1 = P + (size_t)(bm + r1) * KP + kl1 * 8;
  const ushort* pb0 = P + (size_t)(bn + r0) * KP + kl0 * 8;
  const ushort* pb1 = P + (size_t)(bn + r1) * KP + kl1 * 8;

  for (int k0 = 0; k0 < KP; k0 += BK) {
    const uint4 va0 = *(const uint4*)(pa0 + k0);
    const uint4 va1 = *(const uint4*)(pa1 + k0);
    const uint4 vb0 = *(const uint4*)(pb0 + k0);
    const uint4 vb1 = *(const uint4*)(pb1 + k0);
    __syncthreads();
    *(uint4*)&u.st.As[p0 * 8] = va0;
    *(uint4*)&u.st.As[p1 * 8] = va1;
    *(uint4*)&u.st.Bs[p0 * 8] = vb0;
    *(uint4*)&u.st.Bs[p1 * 8] = vb1;
    __syncthreads();
    bf16x8 af[4], bf[4];
    const int kg = lane >> 4;
    #pragma unroll
    for (int f = 0; f < 4; ++f) {
      const int m = wr + f * 16 + (lane & 15);
      const int sa = m * 4 + (kg ^ (m & 3) ^ ((m >> 2) & 1));
      af[f] = *(const bf16x8*)&u.st.As[sa * 8];
      const int n = wc + f * 16 + (lane & 15);
      const int sb = n * 4 + (kg ^ (n & 3) ^ ((n >> 2) & 1));
      bf[f] = *(const bf16x8*)&u.st.Bs[sb * 8];
    }
    #pragma unroll
    for (int fr = 0; fr < 4; ++fr)
      #pragma unroll
      for (int fc = 0; fc < 4; ++fc)
        acc[fr][fc] = __builtin_amdgcn_mfma_f32_16x16x32_bf16(af[fr], bf[fc], acc[fr][fc], 0, 0, 0);
  }
  // all staging reads done before we overwrite the union with the tile
  __syncthreads();
  // dump C frags transposed: tileT[col][row]  (C layout: col=lane&15, row=cq*4+reg)
  const int cq = lane >> 4, cc = lane & 15;
  #pragma unroll
  for (int fr = 0; fr < 4; ++fr) {
    #pragma unroll
    for (int fc = 0; fc < 4; ++fc) {
      const int rb = wr + fr * 16 + cq * 4;
      const int col = wc + fc * 16 + cc;
      u.tileT[col][rb + 0] = acc[fr][fc].x;
      u.tileT[col][rb + 1] = acc[fr][fc].y;
      u.tileT[col][rb + 2] = acc[fr][fc].z;
      u.tileT[col][rb + 3] = acc[fr][fc].w;
    }
  }
  __syncthreads();
  // per-row top-16 scan (128 scanner threads; tileT gives conflict-free reads)
  if (tid < TM) {
    const int gr = bm + tid;
    float v[CT];
    int ix[CT];
    #pragma unroll
    for (int n = 0; n < CT; ++n) { v[n] = -FLT_MAX; ix[n] = -1; }
    for (int c = 0; c < TN; ++c) {
      const int gc = bn + c;
      const float x = (gc == gr) ? -FLT_MAX : u.tileT[c][tid];
      if (x > v[CT - 1]) {
        #pragma unroll
        for (int p = CT - 1; p >= 1; --p) {
          if (x > v[p]) {
            const bool sh = x > v[p - 1];
            v[p] = sh ? v[p - 1] : x;
            ix[p] = sh ? ix[p - 1] : gc;
          }
        }
        if (x > v[0]) { v[0] = x; ix[0] = gc; }
      }
    }
    float* vp = cval + ((size_t)gr * NTILE + blockIdx.x) * CT;
    int* ip = cidx + ((size_t)gr * NTILE + blockIdx.x) * CT;
    #pragma unroll
    for (int n = 0; n < CT; ++n) { vp[n] = v[n]; ip[n] = ix[n]; }
  }
}

// ---------------------------------------------------------------------------
// Merge per-tile candidates -> exact top-10 per row. One WAVE per row.
// Lane l owns tile l's sorted 16-deep list; 16 rounds of butterfly argmax
// with pop-front yield the approx-global top-16, then exact fp32 dots
// (4 lanes per candidate) re-rank and select the exact top-10.
// ---------------------------------------------------------------------------
__global__ __launch_bounds__(256) void merge_topk_kernel(const float* __restrict__ cval,
    const int* __restrict__ cidx, const float* __restrict__ FN,
    int* __restrict__ nidx, float* __restrict__ nval, float* __restrict__ dinv) {
  const int wave = threadIdx.x >> 6, lane = threadIdx.x & 63;
  const int row = blockIdx.x * 4 + wave;

  float v[CT];
  int ix[CT];
  {
    const float4* vp = (const float4*)(cval + ((size_t)row * NTILE + lane) * CT);
    const int4* ip = (const int4*)(cidx + ((size_t)row * NTILE + lane) * CT);
    #pragma unroll
    for (int q = 0; q < 4; ++q) {
      const float4 v4 = vp[q];
      const int4 i4 = ip[q];
      v[q * 4 + 0] = v4.x; v[q * 4 + 1] = v4.y; v[q * 4 + 2] = v4.z; v[q * 4 + 3] = v4.w;
      ix[q * 4 + 0] = i4.x; ix[q * 4 + 1] = i4.y; ix[q * 4 + 2] = i4.z; ix[q * 4 + 3] = i4.w;
    }
  }
  int my_cand = 0;
  #pragma unroll
  for (int sel = 0; sel < CAND; ++sel) {
    float bv = v[0];
    int bl = lane;
    #pragma unroll
    for (int s = 1; s < 64; s <<= 1) {
      const float ov = __shfl_xor(bv, s);
      const int ol = __shfl_xor(bl, s);
      if (ov > bv || (ov == bv && ol < bl)) { bv = ov; bl = ol; }
    }
    const int ci = __shfl(ix[0], bl);
    if ((lane >> 2) == sel) my_cand = ci;
    if (lane == bl) {
      #pragma unroll
      for (int p = 0; p < CT - 1; ++p) { v[p] = v[p + 1]; ix[p] = ix[p + 1]; }
      v[CT - 1] = -FLT_MAX;
      ix[CT - 1] = -1;
    }
  }
  // exact fp32 refinement
  __shared__ float fnrow[4][HID];
  __shared__ float ev[4][CAND];
  __shared__ int eid[4][CAND];
  ((float4*)fnrow[wave])[lane] = ((const float4*)(FN + (size_t)row * HID))[lane];
  __syncthreads();
  const int c = lane >> 2, q = lane & 3;
  {
    float s = 0.f;
    const float* fc = FN + (size_t)my_cand * HID;
    const float* fr = fnrow[wave] + q * 64;
    const float* fcq = fc + q * 64;
    #pragma unroll 8
    for (int k = 0; k < 64; ++k) s += fr[k] * fcq[k];
    s += __shfl_xor(s, 1);
    s += __shfl_xor(s, 2);
    if (q == 0) { ev[wave][c] = s; eid[wave][c] = my_cand; }
  }
  __syncthreads();
  if (lane == 0) {
    unsigned used = 0;
    float outv[TOPK];
    int outi[TOPK];
    float sum = 1.0f;  // diag contributes 1
    #pragma unroll
    for (int sel = 0; sel < TOPK; ++sel) {
      float best = -FLT_MAX;
      int bi = 0;
      #pragma unroll
      for (int k = 0; k < CAND; ++k) {
        if (!((used >> k) & 1u) && ev[wave][k] > best) { best = ev[wave][k]; bi = k; }
      }
      used |= 1u << bi;
      outv[sel] = best;
      outi[sel] = eid[wave][bi];
      sum += fabsf(best);
    }
    const float inv = 1.0f / fmaxf(sum, 1e-12f);
    dinv[row] = inv;
    #pragma unroll
    for (int sel = 0; sel < TOPK; ++sel) {
      nval[row * TOPK + sel] = outv[sel] * inv;
      nidx[row * TOPK + sel] = outi[sel];
    }
  }
}

// ---------------------------------------------------------------------------
// Sparse adj (11 nnz/row) @ T + bias, leaky_relu(0.25).
// ---------------------------------------------------------------------------
__global__ __launch_bounds__(256) void spmm_kernel(const float* __restrict__ T,
    const int* __restrict__ nidx, const float* __restrict__ nval,
    const float* __restrict__ dinv, const float* __restrict__ bias,
    float* __restrict__ H) {
  const int r = blockIdx.x, c = threadIdx.x;
  float acc = dinv[r] * T[(size_t)r * HID + c];
  #pragma unroll
  for (int n = 0; n < TOPK; ++n) {
    acc += nval[r * TOPK + n] * T[(size_t)nidx[r * TOPK + n] * HID + c];
  }
  acc += bias[c];
  H[(size_t)r * HID + c] = acc >= 0.f ? acc : 0.25f * acc;
}

__global__ __launch_bounds__(256) void clf_kernel(const float* __restrict__ H,
    const float* __restrict__ W, const float* __restrict__ b,
    float* __restrict__ L) {
  const int id = blockIdx.x * 256 + threadIdx.x;
  if (id >= NROWS * NCLS) return;
  const int r = id / NCLS, c = id % NCLS;
  float s = b[c];
  const float* hr = H + (size_t)r * HID;
  for (int k = 0; k < HID; ++k) s += hr[k] * W[k * NCLS + c];
  L[id] = s;
}

__global__ __launch_bounds__(256) void fuse_kernel(const float* __restrict__ L,
    const float* __restrict__ attn, float* __restrict__ fused) {
  const int id = blockIdx.x * 256 + threadIdx.x;
  if (id >= NROWS * NCLS) return;
  const float a0 = attn[0], a1 = attn[1], a2 = attn[2];
  const float m = fmaxf(a0, fmaxf(a1, a2));
  const float e0 = expf(a0 - m), e1 = expf(a1 - m), e2 = expf(a2 - m);
  const float inv = 1.0f / (e0 + e1 + e2);
  const float l0 = L[id];
  const float l1 = L[NROWS * NCLS + id];
  const float l2 = L[2 * NROWS * NCLS + id];
  const float s0 = 1.0f / (1.0f + expf(-l0));
  const float s1 = 1.0f / (1.0f + expf(-l1));
  const float s2 = 1.0f / (1.0f + expf(-l2));
  fused[id] = (e0 * s0 + e1 * s1 + e2 * s2) * inv;
}

__global__ __launch_bounds__(128) void head_kernel(const float* __restrict__ fused,
    const float* __restrict__ W1, const float* __restrict__ b1,
    const float* __restrict__ W2, const float* __restrict__ b2,
    float* __restrict__ out) {
  const int r = blockIdx.x, t = threadIdx.x;
  __shared__ float f[NCLS];
  __shared__ float hh[128];
  if (t < NCLS) f[t] = fused[r * NCLS + t];
  __syncthreads();
  float s = b1[t];
  #pragma unroll
  for (int k = 0; k < NCLS; ++k) s += f[k] * W1[k * 128 + t];
  hh[t] = s >= 0.f ? s : 0.25f * s;
  __syncthreads();
  if (t < NCLS) {
    float o = b2[t];
    for (int k = 0; k < 128; ++k) o += hh[k] * W2[k * NCLS + t];
    out[r * NCLS + t] = o;
  }
}

// ---------------------------------------------------------------------------
extern "C" void kernel_launch(void* const* d_in, const int* in_sizes, int n_in,
                              void* d_out, int out_size, void* d_ws, size_t ws_size,
                              hipStream_t stream) {
  const float* x[3]    = {(const float*)d_in[0], (const float*)d_in[1], (const float*)d_in[2]};
  const float* encW[3] = {(const float*)d_in[3], (const float*)d_in[4], (const float*)d_in[5]};
  const float* enc_b = (const float*)d_in[6];
  const float* bn_g  = (const float*)d_in[7];
  const float* bn_b  = (const float*)d_in[8];
  const float* gc1W  = (const float*)d_in[9];
  const float* gc1b  = (const float*)d_in[10];
  const float* gc2W  = (const float*)d_in[11];
  const float* gc2b  = (const float*)d_in[12];
  const float* clfW  = (const float*)d_in[13];
  const float* clfb  = (const float*)d_in[14];
  const float* attn  = (const float*)d_in[15];
  const float* f1W   = (const float*)d_in[16];
  const float* f1b   = (const float*)d_in[17];
  const float* f2W   = (const float*)d_in[18];
  const float* f2b   = (const float*)d_in[19];
  float* out = (float*)d_out;

  // Workspace layout
  float* ws = (float*)d_ws;
  float* A = ws;                           // 8192*256 feat / h1
  float* B = A + (size_t)NROWS * HID;      // 8192*256 fn / h2
  float* C = B + (size_t)NROWS * HID;      // 8192*256 gemm temp
  int*   nidx = (int*)(C + (size_t)NROWS * HID);       // 8192*10
  float* nval = (float*)(nidx + (size_t)NROWS * TOPK); // 8192*10
  float* dinv = nval + (size_t)NROWS * TOPK;           // 8192
  float* logits = dinv + NROWS;                        // 3*8192*5
  float* fused = logits + (size_t)3 * NROWS * NCLS;    // 8192*5
  ushort* Pb = (ushort*)(fused + (size_t)NROWS * NCLS); // 8192*512 bf16 limbs
  float* cval = (float*)(Pb + (size_t)NROWS * KP);      // 8192*64*16 floats
  int*   cidx = (int*)(cval + (size_t)NROWS * NTILE * CT); // 8192*64*16 ints

  const dim3 blk(256);
  for (int i = 0; i < 3; ++i) {
    const int D = in_sizes[i] / NROWS;
    // encoder: A = relu(x @ W + b)
    {
      dim3 g((HID + 63) / 64, (NROWS + 63) / 64);
      gemm_kernel<true, 1><<<g, blk, 0, stream>>>(x[i], encW[i], enc_b + i * HID,
                                                  A, NROWS, HID, D);
    }
    bn_kernel<<<HID, blk, 0, stream>>>(A, bn_g + i * HID, bn_b + i * HID);
    rownorm_kernel<<<NROWS, blk, 0, stream>>>(A, B);
    // two-limb bf16 pack of fn
    pack_kernel<<<NROWS * HID / 256, blk, 0, stream>>>(B, Pb);
    // fused sim MFMA + per-tile top-16, then merge to exact top-10
    {
      dim3 g(NROWS / TN, NROWS / TM);
      simtopk_kernel<<<g, blk, 0, stream>>>(Pb, cval, cidx);
      merge_topk_kernel<<<NROWS / 4, blk, 0, stream>>>(cval, cidx, B, nidx, nval, dinv);
    }
    // gc1
    {
      dim3 g(HID / 64, NROWS / 64);
      gemm_kernel<false, 0><<<g, blk, 0, stream>>>(A, gc1W + (size_t)i * HID * HID,
                                                   nullptr, C, NROWS, HID, HID);
    }
    spmm_kernel<<<NROWS, blk, 0, stream>>>(C, nidx, nval, dinv, gc1b + i * HID, A);
    // gc2
    {
      dim3 g(HID / 64, NROWS / 64);
      gemm_kernel<false, 0><<<g, blk, 0, stream>>>(A, gc2W + (size_t)i * HID * HID,
                                                   nullptr, C, NROWS, HID, HID);
    }
    spmm_kernel<<<NROWS, blk, 0, stream>>>(C, nidx, nval, dinv, gc2b + i * HID, B);
    clf_kernel<<<(NROWS * NCLS + 255) / 256, blk, 0, stream>>>(B, clfW + (size_t)i * HID * NCLS,
                                                               clfb + i * NCLS,
                                                               logits + (size_t)i * NROWS * NCLS);
  }
  fuse_kernel<<<(NROWS * NCLS + 255) / 256, blk, 0, stream>>>(logits, attn, fused);
  head_kernel<<<NROWS, dim3(128), 0, stream>>>(fused, f1W, f1b, f2W, f2b, out);
}

// Round 4
// 1698.972 us; speedup vs baseline: 1.4060x; 1.4060x over previous
//
#include <hip/hip_runtime.h>
#include <cfloat>
#include <cstdint>
#include <cstddef>

#define NROWS 8192
#define HID 256
#define NCLS 5
#define TOPK 10
#define CAND 16
#define KP 512      // packed K = 2*HID (hi|lo limbs)
#define TM 128
#define TN 128
#define BK 32

typedef __bf16 bf16x8 __attribute__((ext_vector_type(8)));
typedef float f32x4 __attribute__((ext_vector_type(4)));

__device__ inline ushort f2bf(float x) {
  unsigned u = __float_as_uint(x);
  unsigned r = (u + 0x7fffu + ((u >> 16) & 1u)) >> 16;  // RNE
  return (ushort)r;
}
__device__ inline float bf2f(ushort b) { return __uint_as_float(((unsigned)b) << 16); }

// ---------------------------------------------------------------------------
// Generic tiled fp32 GEMM (encoder + GCN weight GEMMs): C = act(A@B + bias)
// ---------------------------------------------------------------------------
template<bool BIAS, int ACT>
__global__ __launch_bounds__(256) void gemm_kernel(const float* __restrict__ A,
    const float* __restrict__ B, const float* __restrict__ bias,
    float* __restrict__ C, int M, int N, int K) {
  __shared__ float As[16][68];
  __shared__ float Bs[16][68];
  const int tid = threadIdx.x;
  const int tx = tid & 15, ty = tid >> 4;
  const int bm = blockIdx.y * 64, bn = blockIdx.x * 64;
  float acc[4][4] = {};
  for (int k0 = 0; k0 < K; k0 += 16) {
    {
      const int m = tid >> 2;
      const int kq = (tid & 3) * 4;
      const int gm = bm + m, gk = k0 + kq;
      float a0 = 0.f, a1 = 0.f, a2 = 0.f, a3 = 0.f;
      if (gm < M) {
        const float* p = A + (size_t)gm * K + gk;
        if (gk + 3 < K) {
          float4 v4 = *(const float4*)p;
          a0 = v4.x; a1 = v4.y; a2 = v4.z; a3 = v4.w;
        } else {
          if (gk + 0 < K) a0 = p[0];
          if (gk + 1 < K) a1 = p[1];
          if (gk + 2 < K) a2 = p[2];
        }
      }
      As[kq + 0][m] = a0; As[kq + 1][m] = a1; As[kq + 2][m] = a2; As[kq + 3][m] = a3;
    }
    {
      const int k = tid >> 4;
      const int nq = (tid & 15) * 4;
      const int gk = k0 + k, gn = bn + nq;
      float b0 = 0.f, b1 = 0.f, b2 = 0.f, b3 = 0.f;
      if (gk < K) {
        const float* p = B + (size_t)gk * N + gn;
        if (gn + 3 < N) {
          float4 v4 = *(const float4*)p;
          b0 = v4.x; b1 = v4.y; b2 = v4.z; b3 = v4.w;
        } else {
          if (gn + 0 < N) b0 = p[0];
          if (gn + 1 < N) b1 = p[1];
          if (gn + 2 < N) b2 = p[2];
        }
      }
      Bs[k][nq + 0] = b0; Bs[k][nq + 1] = b1; Bs[k][nq + 2] = b2; Bs[k][nq + 3] = b3;
    }
    __syncthreads();
    #pragma unroll
    for (int kk = 0; kk < 16; ++kk) {
      float a0 = As[kk][ty * 4 + 0], a1 = As[kk][ty * 4 + 1];
      float a2 = As[kk][ty * 4 + 2], a3 = As[kk][ty * 4 + 3];
      float b0 = Bs[kk][tx * 4 + 0], b1 = Bs[kk][tx * 4 + 1];
      float b2 = Bs[kk][tx * 4 + 2], b3 = Bs[kk][tx * 4 + 3];
      acc[0][0] += a0 * b0; acc[0][1] += a0 * b1; acc[0][2] += a0 * b2; acc[0][3] += a0 * b3;
      acc[1][0] += a1 * b0; acc[1][1] += a1 * b1; acc[1][2] += a1 * b2; acc[1][3] += a1 * b3;
      acc[2][0] += a2 * b0; acc[2][1] += a2 * b1; acc[2][2] += a2 * b2; acc[2][3] += a2 * b3;
      acc[3][0] += a3 * b0; acc[3][1] += a3 * b1; acc[3][2] += a3 * b2; acc[3][3] += a3 * b3;
    }
    __syncthreads();
  }
  #pragma unroll
  for (int i = 0; i < 4; ++i) {
    const int gm = bm + ty * 4 + i;
    if (gm >= M) continue;
    #pragma unroll
    for (int jj = 0; jj < 4; ++jj) {
      const int gn = bn + tx * 4 + jj;
      if (gn >= N) continue;
      float v = acc[i][jj];
      if (BIAS) v += bias[gn];
      if (ACT == 1) v = fmaxf(v, 0.f);
      C[(size_t)gm * N + gn] = v;
    }
  }
}

// ---------------------------------------------------------------------------
// BatchNorm1d (training stats, biased var, eps=1e-5), in place.
// ---------------------------------------------------------------------------
__global__ __launch_bounds__(256) void bn_kernel(float* __restrict__ F,
    const float* __restrict__ g, const float* __restrict__ b) {
  const int j = blockIdx.x, t = threadIdx.x;
  float s = 0.f, s2 = 0.f;
  for (int r = t; r < NROWS; r += 256) {
    float v = F[(size_t)r * HID + j];
    s += v; s2 += v * v;
  }
  __shared__ float sh1[256];
  __shared__ float sh2[256];
  sh1[t] = s; sh2[t] = s2;
  __syncthreads();
  for (int st = 128; st > 0; st >>= 1) {
    if (t < st) { sh1[t] += sh1[t + st]; sh2[t] += sh2[t + st]; }
    __syncthreads();
  }
  const float mu = sh1[0] / (float)NROWS;
  const float var = sh2[0] / (float)NROWS - mu * mu;
  const float rstd = rsqrtf(var + 1e-5f);
  const float gg = g[j], bb = b[j];
  for (int r = t; r < NROWS; r += 256) {
    const size_t o = (size_t)r * HID + j;
    F[o] = (F[o] - mu) * rstd * gg + bb;
  }
}

// ---------------------------------------------------------------------------
// L2 row-normalize fn = feat/||feat||.
// ---------------------------------------------------------------------------
__global__ __launch_bounds__(256) void rownorm_kernel(const float* __restrict__ F,
    float* __restrict__ FN) {
  const int r = blockIdx.x, t = threadIdx.x;
  const float v = F[(size_t)r * HID + t];
  __shared__ float sh[256];
  sh[t] = v * v;
  __syncthreads();
  for (int st = 128; st > 0; st >>= 1) {
    if (t < st) sh[t] += sh[t + st];
    __syncthreads();
  }
  const float inv = 1.0f / fmaxf(sqrtf(sh[0]), 1e-12f);
  FN[(size_t)r * HID + t] = v * inv;
}

// ---------------------------------------------------------------------------
// Pack fn into two-limb bf16: P[r] = [bf16(x) | bf16(x - hi)], K = 512.
// ---------------------------------------------------------------------------
__global__ __launch_bounds__(256) void pack_kernel(const float* __restrict__ FN,
    ushort* __restrict__ P) {
  const int id = blockIdx.x * 256 + threadIdx.x;
  const int r = id >> 8, k = id & 255;
  const float x = FN[id];
  const ushort h = f2bf(x);
  const ushort l = f2bf(x - bf2f(h));
  P[(size_t)r * KP + k] = h;
  P[(size_t)r * KP + HID + k] = l;
}

// ---------------------------------------------------------------------------
// sim stripe = P[mbase+..] @ P^T via bf16 MFMA 16x16x32, K=512.
// 128x128 tile, 4 waves (each 64x64 = 4x4 frags), BK=32, XOR-swizzled LDS.
// ---------------------------------------------------------------------------
__global__ __launch_bounds__(256) void simgemm_kernel(const ushort* __restrict__ P,
    float* __restrict__ C, int mbase) {
  __shared__ ushort As[TM * BK];
  __shared__ ushort Bs[TN * BK];
  const int tid = threadIdx.x;
  const int wave = tid >> 6, lane = tid & 63;
  const int bmr = blockIdx.y * TM;
  const int bm = mbase + bmr;
  const int bn = blockIdx.x * TN;
  const int wr = (wave >> 1) * 64;
  const int wc = (wave & 1) * 64;

  f32x4 acc[4][4];
  const f32x4 zero = {0.f, 0.f, 0.f, 0.f};
  #pragma unroll
  for (int i = 0; i < 4; ++i)
    #pragma unroll
    for (int j = 0; j < 4; ++j) acc[i][j] = zero;

  const int p0 = tid, p1 = tid + 256;
  const int r0 = p0 >> 2, kl0 = (p0 & 3) ^ ((r0 & 3) ^ ((r0 >> 2) & 1));
  const int r1 = p1 >> 2, kl1 = (p1 & 3) ^ ((r1 & 3) ^ ((r1 >> 2) & 1));
  const ushort* pa0 = P + (size_t)(bm + r0) * KP + kl0 * 8;
  const ushort* pa1 = P + (size_t)(bm + r1) * KP + kl1 * 8;
  const ushort* pb0 = P + (size_t)(bn + r0) * KP + kl0 * 8;
  const ushort* pb1 = P + (size_t)(bn + r1) * KP + kl1 * 8;

  for (int k0 = 0; k0 < KP; k0 += BK) {
    const uint4 va0 = *(const uint4*)(pa0 + k0);
    const uint4 va1 = *(const uint4*)(pa1 + k0);
    const uint4 vb0 = *(const uint4*)(pb0 + k0);
    const uint4 vb1 = *(const uint4*)(pb1 + k0);
    __syncthreads();
    *(uint4*)&As[p0 * 8] = va0;
    *(uint4*)&As[p1 * 8] = va1;
    *(uint4*)&Bs[p0 * 8] = vb0;
    *(uint4*)&Bs[p1 * 8] = vb1;
    __syncthreads();
    bf16x8 af[4], bf[4];
    const int kg = lane >> 4;
    #pragma unroll
    for (int f = 0; f < 4; ++f) {
      const int m = wr + f * 16 + (lane & 15);
      const int sa = m * 4 + (kg ^ (m & 3) ^ ((m >> 2) & 1));
      af[f] = *(const bf16x8*)&As[sa * 8];
      const int n = wc + f * 16 + (lane & 15);
      const int sb = n * 4 + (kg ^ (n & 3) ^ ((n >> 2) & 1));
      bf[f] = *(const bf16x8*)&Bs[sb * 8];
    }
    #pragma unroll
    for (int fr = 0; fr < 4; ++fr)
      #pragma unroll
      for (int fc = 0; fc < 4; ++fc)
        acc[fr][fc] = __builtin_amdgcn_mfma_f32_16x16x32_bf16(af[fr], bf[fc], acc[fr][fc], 0, 0, 0);
  }
  const int cq = lane >> 4, cc = lane & 15;
  #pragma unroll
  for (int fr = 0; fr < 4; ++fr) {
    #pragma unroll
    for (int fc = 0; fc < 4; ++fc) {
      const int rb = bmr + wr + fr * 16 + cq * 4;
      const int col = bn + wc + fc * 16 + cc;
      float* cp = C + (size_t)rb * NROWS + col;
      cp[0] = acc[fr][fc].x;
      cp[(size_t)1 * NROWS] = acc[fr][fc].y;
      cp[(size_t)2 * NROWS] = acc[fr][fc].z;
      cp[(size_t)3 * NROWS] = acc[fr][fc].w;
    }
  }
}

// ---------------------------------------------------------------------------
// Per-row top-K from approx sim stripe, one WAVE per row.
// float4 loads with next-quad prefetch hide the load latency that bounded
// the R2 version (128 dependent scalar loads). Then wave argmax merge ->
// 16 candidates, exact fp32 re-rank -> exact top-10.
// ---------------------------------------------------------------------------
__global__ __launch_bounds__(256) void topk_kernel(const float* __restrict__ S, int base,
    const float* __restrict__ FN, int* __restrict__ nidx, float* __restrict__ nval,
    float* __restrict__ dinv) {
  const int wave = threadIdx.x >> 6, lane = threadIdx.x & 63;
  const int lr = blockIdx.x * 4 + wave;
  const int row = base + lr;
  const float4* rowp = (const float4*)(S + (size_t)lr * NROWS);  // 2048 float4

  float v[CAND];
  int ix[CAND];
  #pragma unroll
  for (int n = 0; n < CAND; ++n) { v[n] = -FLT_MAX; ix[n] = -1; }

  float4 cur = rowp[lane];
  #pragma unroll 4
  for (int it = 0; it < 32; ++it) {
    float4 nxt;
    if (it < 31) nxt = rowp[(it + 1) * 64 + lane];  // prefetch before branchy body
    const int c0 = (it * 64 + lane) * 4;
    float xs[4] = {cur.x, cur.y, cur.z, cur.w};
    #pragma unroll
    for (int e = 0; e < 4; ++e) {
      const int j = c0 + e;
      const float x = (j == row) ? -FLT_MAX : xs[e];
      if (x > v[CAND - 1]) {
        #pragma unroll
        for (int p = CAND - 1; p >= 1; --p) {
          if (x > v[p]) {
            const bool sh = x > v[p - 1];
            v[p] = sh ? v[p - 1] : x;
            ix[p] = sh ? ix[p - 1] : j;
          }
        }
        if (x > v[0]) { v[0] = x; ix[0] = j; }
      }
    }
    cur = nxt;
  }

  // wave merge: 16 rounds of butterfly argmax over heads, winner pops front
  int my_cand = 0;
  #pragma unroll
  for (int sel = 0; sel < CAND; ++sel) {
    float bv = v[0];
    int bl = lane;
    #pragma unroll
    for (int s = 1; s < 64; s <<= 1) {
      const float ov = __shfl_xor(bv, s);
      const int ol = __shfl_xor(bl, s);
      if (ov > bv || (ov == bv && ol < bl)) { bv = ov; bl = ol; }
    }
    const int ci = __shfl(ix[0], bl);
    if ((lane >> 2) == sel) my_cand = ci;
    if (lane == bl) {
      #pragma unroll
      for (int p = 0; p < CAND - 1; ++p) { v[p] = v[p + 1]; ix[p] = ix[p + 1]; }
      v[CAND - 1] = -FLT_MAX;
      ix[CAND - 1] = -1;
    }
  }
  // exact fp32 refinement (4 lanes per candidate)
  __shared__ float fnrow[4][HID];
  __shared__ float ev[4][CAND];
  __shared__ int eid[4][CAND];
  ((float4*)fnrow[wave])[lane] = ((const float4*)(FN + (size_t)row * HID))[lane];
  __syncthreads();
  const int c = lane >> 2, q = lane & 3;
  {
    float s = 0.f;
    const float* fc = FN + (size_t)my_cand * HID;
    const float* fr = fnrow[wave] + q * 64;
    const float* fcq = fc + q * 64;
    #pragma unroll 8
    for (int k = 0; k < 64; ++k) s += fr[k] * fcq[k];
    s += __shfl_xor(s, 1);
    s += __shfl_xor(s, 2);
    if (q == 0) { ev[wave][c] = s; eid[wave][c] = my_cand; }
  }
  __syncthreads();
  if (lane == 0) {
    unsigned used = 0;
    float outv[TOPK];
    int outi[TOPK];
    float sum = 1.0f;  // diag contributes 1
    #pragma unroll
    for (int sel = 0; sel < TOPK; ++sel) {
      float best = -FLT_MAX;
      int bi = 0;
      #pragma unroll
      for (int k = 0; k < CAND; ++k) {
        if (!((used >> k) & 1u) && ev[wave][k] > best) { best = ev[wave][k]; bi = k; }
      }
      used |= 1u << bi;
      outv[sel] = best;
      outi[sel] = eid[wave][bi];
      sum += fabsf(best);
    }
    const float inv = 1.0f / fmaxf(sum, 1e-12f);
    dinv[row] = inv;
    #pragma unroll
    for (int sel = 0; sel < TOPK; ++sel) {
      nval[row * TOPK + sel] = outv[sel] * inv;
      nidx[row * TOPK + sel] = outi[sel];
    }
  }
}

// ---------------------------------------------------------------------------
// Sparse adj (11 nnz/row) @ T + bias, leaky_relu(0.25).
// ---------------------------------------------------------------------------
__global__ __launch_bounds__(256) void spmm_kernel(const float* __restrict__ T,
    const int* __restrict__ nidx, const float* __restrict__ nval,
    const float* __restrict__ dinv, const float* __restrict__ bias,
    float* __restrict__ H) {
  const int r = blockIdx.x, c = threadIdx.x;
  float acc = dinv[r] * T[(size_t)r * HID + c];
  #pragma unroll
  for (int n = 0; n < TOPK; ++n) {
    acc += nval[r * TOPK + n] * T[(size_t)nidx[r * TOPK + n] * HID + c];
  }
  acc += bias[c];
  H[(size_t)r * HID + c] = acc >= 0.f ? acc : 0.25f * acc;
}

__global__ __launch_bounds__(256) void clf_kernel(const float* __restrict__ H,
    const float* __restrict__ W, const float* __restrict__ b,
    float* __restrict__ L) {
  const int id = blockIdx.x * 256 + threadIdx.x;
  if (id >= NROWS * NCLS) return;
  const int r = id / NCLS, c = id % NCLS;
  float s = b[c];
  const float* hr = H + (size_t)r * HID;
  for (int k = 0; k < HID; ++k) s += hr[k] * W[k * NCLS + c];
  L[id] = s;
}

__global__ __launch_bounds__(256) void fuse_kernel(const float* __restrict__ L,
    const float* __restrict__ attn, float* __restrict__ fused) {
  const int id = blockIdx.x * 256 + threadIdx.x;
  if (id >= NROWS * NCLS) return;
  const float a0 = attn[0], a1 = attn[1], a2 = attn[2];
  const float m = fmaxf(a0, fmaxf(a1, a2));
  const float e0 = expf(a0 - m), e1 = expf(a1 - m), e2 = expf(a2 - m);
  const float inv = 1.0f / (e0 + e1 + e2);
  const float l0 = L[id];
  const float l1 = L[NROWS * NCLS + id];
  const float l2 = L[2 * NROWS * NCLS + id];
  const float s0 = 1.0f / (1.0f + expf(-l0));
  const float s1 = 1.0f / (1.0f + expf(-l1));
  const float s2 = 1.0f / (1.0f + expf(-l2));
  fused[id] = (e0 * s0 + e1 * s1 + e2 * s2) * inv;
}

__global__ __launch_bounds__(128) void head_kernel(const float* __restrict__ fused,
    const float* __restrict__ W1, const float* __restrict__ b1,
    const float* __restrict__ W2, const float* __restrict__ b2,
    float* __restrict__ out) {
  const int r = blockIdx.x, t = threadIdx.x;
  __shared__ float f[NCLS];
  __shared__ float hh[128];
  if (t < NCLS) f[t] = fused[r * NCLS + t];
  __syncthreads();
  float s = b1[t];
  #pragma unroll
  for (int k = 0; k < NCLS; ++k) s += f[k] * W1[k * 128 + t];
  hh[t] = s >= 0.f ? s : 0.25f * s;
  __syncthreads();
  if (t < NCLS) {
    float o = b2[t];
    for (int k = 0; k < 128; ++k) o += hh[k] * W2[k * NCLS + t];
    out[r * NCLS + t] = o;
  }
}

// ---------------------------------------------------------------------------
extern "C" void kernel_launch(void* const* d_in, const int* in_sizes, int n_in,
                              void* d_out, int out_size, void* d_ws, size_t ws_size,
                              hipStream_t stream) {
  const float* x[3]    = {(const float*)d_in[0], (const float*)d_in[1], (const float*)d_in[2]};
  const float* encW[3] = {(const float*)d_in[3], (const float*)d_in[4], (const float*)d_in[5]};
  const float* enc_b = (const float*)d_in[6];
  const float* bn_g  = (const float*)d_in[7];
  const float* bn_b  = (const float*)d_in[8];
  const float* gc1W  = (const float*)d_in[9];
  const float* gc1b  = (const float*)d_in[10];
  const float* gc2W  = (const float*)d_in[11];
  const float* gc2b  = (const float*)d_in[12];
  const float* clfW  = (const float*)d_in[13];
  const float* clfb  = (const float*)d_in[14];
  const float* attn  = (const float*)d_in[15];
  const float* f1W   = (const float*)d_in[16];
  const float* f1b   = (const float*)d_in[17];
  const float* f2W   = (const float*)d_in[18];
  const float* f2b   = (const float*)d_in[19];
  float* out = (float*)d_out;

  // Workspace layout
  float* ws = (float*)d_ws;
  float* A = ws;                           // 8192*256 feat / h1
  float* B = A + (size_t)NROWS * HID;      // 8192*256 fn / h2
  float* C = B + (size_t)NROWS * HID;      // 8192*256 gemm temp
  int*   nidx = (int*)(C + (size_t)NROWS * HID);       // 8192*10
  float* nval = (float*)(nidx + (size_t)NROWS * TOPK); // 8192*10
  float* dinv = nval + (size_t)NROWS * TOPK;           // 8192
  float* logits = dinv + NROWS;                        // 3*8192*5
  float* fused = logits + (size_t)3 * NROWS * NCLS;    // 8192*5
  ushort* Pb = (ushort*)(fused + (size_t)NROWS * NCLS); // 8192*512 bf16 limbs
  float* stripe = (float*)(Pb + (size_t)NROWS * KP);    // SR * 8192
  const size_t fixed_bytes = (size_t)((char*)stripe - (char*)ws);
  const size_t avail = (ws_size > fixed_bytes) ? (ws_size - fixed_bytes) : 0;
  int SR = 128;
  while (SR < NROWS && (size_t)SR * 2 * NROWS * sizeof(float) <= avail) SR <<= 1;

  const dim3 blk(256);
  for (int i = 0; i < 3; ++i) {
    const int D = in_sizes[i] / NROWS;
    // encoder: A = relu(x @ W + b)
    {
      dim3 g((HID + 63) / 64, (NROWS + 63) / 64);
      gemm_kernel<true, 1><<<g, blk, 0, stream>>>(x[i], encW[i], enc_b + i * HID,
                                                  A, NROWS, HID, D);
    }
    bn_kernel<<<HID, blk, 0, stream>>>(A, bn_g + i * HID, bn_b + i * HID);
    rownorm_kernel<<<NROWS, blk, 0, stream>>>(A, B);
    // two-limb bf16 pack of fn
    pack_kernel<<<NROWS * HID / 256, blk, 0, stream>>>(B, Pb);
    // sim stripes (MFMA) + per-row top-k with exact refinement
    for (int s0 = 0; s0 < NROWS; s0 += SR) {
      dim3 g(NROWS / TN, SR / TM);
      simgemm_kernel<<<g, blk, 0, stream>>>(Pb, stripe, s0);
      topk_kernel<<<SR / 4, blk, 0, stream>>>(stripe, s0, B, nidx, nval, dinv);
    }
    // gc1
    {
      dim3 g(HID / 64, NROWS / 64);
      gemm_kernel<false, 0><<<g, blk, 0, stream>>>(A, gc1W + (size_t)i * HID * HID,
                                                   nullptr, C, NROWS, HID, HID);
    }
    spmm_kernel<<<NROWS, blk, 0, stream>>>(C, nidx, nval, dinv, gc1b + i * HID, A);
    // gc2
    {
      dim3 g(HID / 64, NROWS / 64);
      gemm_kernel<false, 0><<<g, blk, 0, stream>>>(A, gc2W + (size_t)i * HID * HID,
                                                   nullptr, C, NROWS, HID, HID);
    }
    spmm_kernel<<<NROWS, blk, 0, stream>>>(C, nidx, nval, dinv, gc2b + i * HID, B);
    clf_kernel<<<(NROWS * NCLS + 255) / 256, blk, 0, stream>>>(B, clfW + (size_t)i * HID * NCLS,
                                                               clfb + i * NCLS,
                                                               logits + (size_t)i * NROWS * NCLS);
  }
  fuse_kernel<<<(NROWS * NCLS + 255) / 256, blk, 0, stream>>>(logits, attn, fused);
  head_kernel<<<NROWS, dim3(128), 0, stream>>>(fused, f1W, f1b, f2W, f2b, out);
}

// Round 5
// 1613.970 us; speedup vs baseline: 1.4800x; 1.0527x over previous
//
#include <hip/hip_runtime.h>
#include <cfloat>
#include <cstdint>
#include <cstddef>

#define NROWS 8192
#define HID 256
#define NCLS 5
#define TOPK 10
#define CBUF 128    // candidate buffer cap per row (typ. ~20-40 used)
#define KP 512      // packed K = 2*HID (hi|lo limbs)
#define TM 128
#define TN 128
#define BK 32

typedef __bf16 bf16x8 __attribute__((ext_vector_type(8)));
typedef float f32x4 __attribute__((ext_vector_type(4)));

__device__ inline ushort f2bf(float x) {
  unsigned u = __float_as_uint(x);
  unsigned r = (u + 0x7fffu + ((u >> 16) & 1u)) >> 16;  // RNE
  return (ushort)r;
}
__device__ inline float bf2f(ushort b) { return __uint_as_float(((unsigned)b) << 16); }

// async global->LDS 16B/lane; LDS dest is wave-uniform base + lane*16
__device__ __forceinline__ void load_lds16(const void* g, void* l) {
  __builtin_amdgcn_global_load_lds(
      (const __attribute__((address_space(1))) void*)g,
      (__attribute__((address_space(3))) void*)l, 16, 0, 0);
}

// ---------------------------------------------------------------------------
// Generic tiled fp32 GEMM (encoder + GCN weight GEMMs): C = act(A@B + bias)
// ---------------------------------------------------------------------------
template<bool BIAS, int ACT>
__global__ __launch_bounds__(256) void gemm_kernel(const float* __restrict__ A,
    const float* __restrict__ B, const float* __restrict__ bias,
    float* __restrict__ C, int M, int N, int K) {
  __shared__ float As[16][68];
  __shared__ float Bs[16][68];
  const int tid = threadIdx.x;
  const int tx = tid & 15, ty = tid >> 4;
  const int bm = blockIdx.y * 64, bn = blockIdx.x * 64;
  float acc[4][4] = {};
  for (int k0 = 0; k0 < K; k0 += 16) {
    {
      const int m = tid >> 2;
      const int kq = (tid & 3) * 4;
      const int gm = bm + m, gk = k0 + kq;
      float a0 = 0.f, a1 = 0.f, a2 = 0.f, a3 = 0.f;
      if (gm < M) {
        const float* p = A + (size_t)gm * K + gk;
        if (gk + 3 < K) {
          float4 v4 = *(const float4*)p;
          a0 = v4.x; a1 = v4.y; a2 = v4.z; a3 = v4.w;
        } else {
          if (gk + 0 < K) a0 = p[0];
          if (gk + 1 < K) a1 = p[1];
          if (gk + 2 < K) a2 = p[2];
        }
      }
      As[kq + 0][m] = a0; As[kq + 1][m] = a1; As[kq + 2][m] = a2; As[kq + 3][m] = a3;
    }
    {
      const int k = tid >> 4;
      const int nq = (tid & 15) * 4;
      const int gk = k0 + k, gn = bn + nq;
      float b0 = 0.f, b1 = 0.f, b2 = 0.f, b3 = 0.f;
      if (gk < K) {
        const float* p = B + (size_t)gk * N + gn;
        if (gn + 3 < N) {
          float4 v4 = *(const float4*)p;
          b0 = v4.x; b1 = v4.y; b2 = v4.z; b3 = v4.w;
        } else {
          if (gn + 0 < N) b0 = p[0];
          if (gn + 1 < N) b1 = p[1];
          if (gn + 2 < N) b2 = p[2];
        }
      }
      Bs[k][nq + 0] = b0; Bs[k][nq + 1] = b1; Bs[k][nq + 2] = b2; Bs[k][nq + 3] = b3;
    }
    __syncthreads();
    #pragma unroll
    for (int kk = 0; kk < 16; ++kk) {
      float a0 = As[kk][ty * 4 + 0], a1 = As[kk][ty * 4 + 1];
      float a2 = As[kk][ty * 4 + 2], a3 = As[kk][ty * 4 + 3];
      float b0 = Bs[kk][tx * 4 + 0], b1 = Bs[kk][tx * 4 + 1];
      float b2 = Bs[kk][tx * 4 + 2], b3 = Bs[kk][tx * 4 + 3];
      acc[0][0] += a0 * b0; acc[0][1] += a0 * b1; acc[0][2] += a0 * b2; acc[0][3] += a0 * b3;
      acc[1][0] += a1 * b0; acc[1][1] += a1 * b1; acc[1][2] += a1 * b2; acc[1][3] += a1 * b3;
      acc[2][0] += a2 * b0; acc[2][1] += a2 * b1; acc[2][2] += a2 * b2; acc[2][3] += a2 * b3;
      acc[3][0] += a3 * b0; acc[3][1] += a3 * b1; acc[3][2] += a3 * b2; acc[3][3] += a3 * b3;
    }
    __syncthreads();
  }
  #pragma unroll
  for (int i = 0; i < 4; ++i) {
    const int gm = bm + ty * 4 + i;
    if (gm >= M) continue;
    #pragma unroll
    for (int jj = 0; jj < 4; ++jj) {
      const int gn = bn + tx * 4 + jj;
      if (gn >= N) continue;
      float v = acc[i][jj];
      if (BIAS) v += bias[gn];
      if (ACT == 1) v = fmaxf(v, 0.f);
      C[(size_t)gm * N + gn] = v;
    }
  }
}

// ---------------------------------------------------------------------------
// BatchNorm1d (training stats, biased var, eps=1e-5), in place.
// ---------------------------------------------------------------------------
__global__ __launch_bounds__(256) void bn_kernel(float* __restrict__ F,
    const float* __restrict__ g, const float* __restrict__ b) {
  const int j = blockIdx.x, t = threadIdx.x;
  float s = 0.f, s2 = 0.f;
  for (int r = t; r < NROWS; r += 256) {
    float v = F[(size_t)r * HID + j];
    s += v; s2 += v * v;
  }
  __shared__ float sh1[256];
  __shared__ float sh2[256];
  sh1[t] = s; sh2[t] = s2;
  __syncthreads();
  for (int st = 128; st > 0; st >>= 1) {
    if (t < st) { sh1[t] += sh1[t + st]; sh2[t] += sh2[t + st]; }
    __syncthreads();
  }
  const float mu = sh1[0] / (float)NROWS;
  const float var = sh2[0] / (float)NROWS - mu * mu;
  const float rstd = rsqrtf(var + 1e-5f);
  const float gg = g[j], bb = b[j];
  for (int r = t; r < NROWS; r += 256) {
    const size_t o = (size_t)r * HID + j;
    F[o] = (F[o] - mu) * rstd * gg + bb;
  }
}

// ---------------------------------------------------------------------------
// L2 row-normalize fn = feat/||feat||.
// ---------------------------------------------------------------------------
__global__ __launch_bounds__(256) void rownorm_kernel(const float* __restrict__ F,
    float* __restrict__ FN) {
  const int r = blockIdx.x, t = threadIdx.x;
  const float v = F[(size_t)r * HID + t];
  __shared__ float sh[256];
  sh[t] = v * v;
  __syncthreads();
  for (int st = 128; st > 0; st >>= 1) {
    if (t < st) sh[t] += sh[t + st];
    __syncthreads();
  }
  const float inv = 1.0f / fmaxf(sqrtf(sh[0]), 1e-12f);
  FN[(size_t)r * HID + t] = v * inv;
}

// ---------------------------------------------------------------------------
// Pack fn into two-limb bf16: P[r] = [bf16(x) | bf16(x - hi)], K = 512.
// ---------------------------------------------------------------------------
__global__ __launch_bounds__(256) void pack_kernel(const float* __restrict__ FN,
    ushort* __restrict__ P) {
  const int id = blockIdx.x * 256 + threadIdx.x;
  const int r = id >> 8, k = id & 255;
  const float x = FN[id];
  const ushort h = f2bf(x);
  const ushort l = f2bf(x - bf2f(h));
  P[(size_t)r * KP + k] = h;
  P[(size_t)r * KP + HID + k] = l;
}

// ---------------------------------------------------------------------------
// sim stripe = P[mbase+..] @ P^T via bf16 MFMA 16x16x32, K=512.
// 128x128 tile, 4 waves, BK=32, XOR-swizzled LDS, global_load_lds staging
// (width 16; LDS slot = wave-uniform base + lane*16, matches p0/p1 layout).
// ---------------------------------------------------------------------------
__global__ __launch_bounds__(256) void simgemm_kernel(const ushort* __restrict__ P,
    float* __restrict__ C, int mbase) {
  __shared__ ushort As[TM * BK];
  __shared__ ushort Bs[TN * BK];
  const int tid = threadIdx.x;
  const int wave = tid >> 6, lane = tid & 63;
  const int bmr = blockIdx.y * TM;
  const int bm = mbase + bmr;
  const int bn = blockIdx.x * TN;
  const int wr = (wave >> 1) * 64;
  const int wc = (wave & 1) * 64;

  f32x4 acc[4][4];
  const f32x4 zero = {0.f, 0.f, 0.f, 0.f};
  #pragma unroll
  for (int i = 0; i < 4; ++i)
    #pragma unroll
    for (int j = 0; j < 4; ++j) acc[i][j] = zero;

  const int p0 = tid, p1 = tid + 256;
  const int r0 = p0 >> 2, kl0 = (p0 & 3) ^ ((r0 & 3) ^ ((r0 >> 2) & 1));
  const int r1 = p1 >> 2, kl1 = (p1 & 3) ^ ((r1 & 3) ^ ((r1 >> 2) & 1));
  const ushort* pa0 = P + (size_t)(bm + r0) * KP + kl0 * 8;
  const ushort* pa1 = P + (size_t)(bm + r1) * KP + kl1 * 8;
  const ushort* pb0 = P + (size_t)(bn + r0) * KP + kl0 * 8;
  const ushort* pb1 = P + (size_t)(bn + r1) * KP + kl1 * 8;

  for (int k0 = 0; k0 < KP; k0 += BK) {
    __syncthreads();  // previous iteration's LDS readers done
    load_lds16(pa0 + k0, &As[p0 * 8]);
    load_lds16(pa1 + k0, &As[p1 * 8]);
    load_lds16(pb0 + k0, &Bs[p0 * 8]);
    load_lds16(pb1 + k0, &Bs[p1 * 8]);
    __syncthreads();  // vmcnt(0) drain before barrier covers the async loads
    bf16x8 af[4], bf[4];
    const int kg = lane >> 4;
    #pragma unroll
    for (int f = 0; f < 4; ++f) {
      const int m = wr + f * 16 + (lane & 15);
      const int sa = m * 4 + (kg ^ (m & 3) ^ ((m >> 2) & 1));
      af[f] = *(const bf16x8*)&As[sa * 8];
      const int n = wc + f * 16 + (lane & 15);
      const int sb = n * 4 + (kg ^ (n & 3) ^ ((n >> 2) & 1));
      bf[f] = *(const bf16x8*)&Bs[sb * 8];
    }
    #pragma unroll
    for (int fr = 0; fr < 4; ++fr)
      #pragma unroll
      for (int fc = 0; fc < 4; ++fc)
        acc[fr][fc] = __builtin_amdgcn_mfma_f32_16x16x32_bf16(af[fr], bf[fc], acc[fr][fc], 0, 0, 0);
  }
  const int cq = lane >> 4, cc = lane & 15;
  #pragma unroll
  for (int fr = 0; fr < 4; ++fr) {
    #pragma unroll
    for (int fc = 0; fc < 4; ++fc) {
      const int rb = bmr + wr + fr * 16 + cq * 4;
      const int col = bn + wc + fc * 16 + cc;
      float* cp = C + (size_t)rb * NROWS + col;
      cp[0] = acc[fr][fc].x;
      cp[(size_t)1 * NROWS] = acc[fr][fc].y;
      cp[(size_t)2 * NROWS] = acc[fr][fc].z;
      cp[(size_t)3 * NROWS] = acc[fr][fc].w;
    }
  }
}

// ---------------------------------------------------------------------------
// Threshold-based per-row top-K. One WAVE per row.
// Pass A: per-lane max (divergence-free) -> tau = 16th largest of 64 lane
//         maxes (butterfly argmax-pop). Every true top-16 element >= tau.
// Pass B: compact all elements >= tau (typ ~20-40) into LDS (L2-hot reread).
// Then exact fp32 dots for ALL candidates, exact top-10 selection.
// ---------------------------------------------------------------------------
__global__ __launch_bounds__(256) void topk_kernel(const float* __restrict__ S, int base,
    const float* __restrict__ FN, int* __restrict__ nidx, float* __restrict__ nval,
    float* __restrict__ dinv) {
  const int wave = threadIdx.x >> 6, lane = threadIdx.x & 63;
  const int lr = blockIdx.x * 4 + wave;
  const int row = base + lr;
  const float4* rowp = (const float4*)(S + (size_t)lr * NROWS);  // 2048 float4

  // ---- Pass A: per-lane max, self masked
  float m = -FLT_MAX;
  for (int it = 0; it < 32; ++it) {
    const float4 q = rowp[it * 64 + lane];
    const int j0 = (it * 64 + lane) * 4;
    m = fmaxf(m, (j0 + 0 == row) ? -FLT_MAX : q.x);
    m = fmaxf(m, (j0 + 1 == row) ? -FLT_MAX : q.y);
    m = fmaxf(m, (j0 + 2 == row) ? -FLT_MAX : q.z);
    m = fmaxf(m, (j0 + 3 == row) ? -FLT_MAX : q.w);
  }
  // tau = 16th largest of the 64 lane maxes
  float tau = m;
  {
    float cur = m;
    #pragma unroll
    for (int sel = 0; sel < 16; ++sel) {
      float bv = cur;
      int bl = lane;
      #pragma unroll
      for (int s = 1; s < 64; s <<= 1) {
        const float ov = __shfl_xor(bv, s);
        const int ol = __shfl_xor(bl, s);
        if (ov > bv || (ov == bv && ol < bl)) { bv = ov; bl = ol; }
      }
      tau = bv;
      if (lane == bl) cur = -FLT_MAX;
    }
  }

  // ---- Pass B: compact candidates >= tau
  __shared__ int ccnt[4];
  __shared__ float cbf[4][CBUF];
  __shared__ int cbi[4][CBUF];
  __shared__ float fnrow[4][HID];
  __shared__ float ev[4][CBUF];
  if (lane == 0) ccnt[wave] = 0;
  ((float4*)fnrow[wave])[lane] = ((const float4*)(FN + (size_t)row * HID))[lane];
  __syncthreads();
  for (int it = 0; it < 32; ++it) {
    const float4 q = rowp[it * 64 + lane];
    const int j0 = (it * 64 + lane) * 4;
    const float xs[4] = {q.x, q.y, q.z, q.w};
    #pragma unroll
    for (int e = 0; e < 4; ++e) {
      const int j = j0 + e;
      const float x = (j == row) ? -FLT_MAX : xs[e];
      if (x >= tau) {
        const int pos = atomicAdd(&ccnt[wave], 1);
        if (pos < CBUF) { cbf[wave][pos] = x; cbi[wave][pos] = j; }
      }
    }
  }
  __syncthreads();
  const int cnt = min(ccnt[wave], CBUF);

  // ---- exact fp32 refinement of every candidate (4 lanes per candidate)
  const int c = lane >> 2, q4 = lane & 3;
  for (int b0 = 0; b0 < cnt; b0 += 16) {
    const int ci = b0 + c;
    const int cand = (ci < cnt) ? cbi[wave][ci] : 0;
    float s = 0.f;
    const float* fc = FN + (size_t)cand * HID + q4 * 64;
    const float* fr = fnrow[wave] + q4 * 64;
    #pragma unroll 8
    for (int k = 0; k < 64; ++k) s += fr[k] * fc[k];
    s += __shfl_xor(s, 1);
    s += __shfl_xor(s, 2);
    if (q4 == 0 && ci < cnt) ev[wave][ci] = s;
  }
  __syncthreads();

  // ---- exact top-10 selection (parallel argmax, pop by -inf)
  float outv[TOPK];
  int outi[TOPK];
  float sum = 1.0f;  // diag contributes 1
  #pragma unroll
  for (int sel = 0; sel < TOPK; ++sel) {
    float bv = -FLT_MAX;
    int bp = 0;
    if (lane < cnt) { bv = ev[wave][lane]; bp = lane; }
    if (lane + 64 < cnt) {
      const float v2 = ev[wave][lane + 64];
      if (v2 > bv) { bv = v2; bp = lane + 64; }
    }
    #pragma unroll
    for (int s = 1; s < 64; s <<= 1) {
      const float ov = __shfl_xor(bv, s);
      const int op = __shfl_xor(bp, s);
      if (ov > bv || (ov == bv && op < bp)) { bv = ov; bp = op; }
    }
    outv[sel] = bv;
    outi[sel] = bp;
    sum += fabsf(bv);
    if (lane == 0) ev[wave][bp] = -FLT_MAX;  // pop (wave-ordered LDS)
  }
  if (lane == 0) {
    const float inv = 1.0f / fmaxf(sum, 1e-12f);
    dinv[row] = inv;
    #pragma unroll
    for (int sel = 0; sel < TOPK; ++sel) {
      nval[row * TOPK + sel] = outv[sel] * inv;
      nidx[row * TOPK + sel] = cbi[wave][outi[sel]];
    }
  }
}

// ---------------------------------------------------------------------------
// Sparse adj (11 nnz/row) @ T + bias, leaky_relu(0.25).
// ---------------------------------------------------------------------------
__global__ __launch_bounds__(256) void spmm_kernel(const float* __restrict__ T,
    const int* __restrict__ nidx, const float* __restrict__ nval,
    const float* __restrict__ dinv, const float* __restrict__ bias,
    float* __restrict__ H) {
  const int r = blockIdx.x, c = threadIdx.x;
  float acc = dinv[r] * T[(size_t)r * HID + c];
  #pragma unroll
  for (int n = 0; n < TOPK; ++n) {
    acc += nval[r * TOPK + n] * T[(size_t)nidx[r * TOPK + n] * HID + c];
  }
  acc += bias[c];
  H[(size_t)r * HID + c] = acc >= 0.f ? acc : 0.25f * acc;
}

__global__ __launch_bounds__(256) void clf_kernel(const float* __restrict__ H,
    const float* __restrict__ W, const float* __restrict__ b,
    float* __restrict__ L) {
  const int id = blockIdx.x * 256 + threadIdx.x;
  if (id >= NROWS * NCLS) return;
  const int r = id / NCLS, c = id % NCLS;
  float s = b[c];
  const float* hr = H + (size_t)r * HID;
  for (int k = 0; k < HID; ++k) s += hr[k] * W[k * NCLS + c];
  L[id] = s;
}

__global__ __launch_bounds__(256) void fuse_kernel(const float* __restrict__ L,
    const float* __restrict__ attn, float* __restrict__ fused) {
  const int id = blockIdx.x * 256 + threadIdx.x;
  if (id >= NROWS * NCLS) return;
  const float a0 = attn[0], a1 = attn[1], a2 = attn[2];
  const float m = fmaxf(a0, fmaxf(a1, a2));
  const float e0 = expf(a0 - m), e1 = expf(a1 - m), e2 = expf(a2 - m);
  const float inv = 1.0f / (e0 + e1 + e2);
  const float l0 = L[id];
  const float l1 = L[NROWS * NCLS + id];
  const float l2 = L[2 * NROWS * NCLS + id];
  const float s0 = 1.0f / (1.0f + expf(-l0));
  const float s1 = 1.0f / (1.0f + expf(-l1));
  const float s2 = 1.0f / (1.0f + expf(-l2));
  fused[id] = (e0 * s0 + e1 * s1 + e2 * s2) * inv;
}

__global__ __launch_bounds__(128) void head_kernel(const float* __restrict__ fused,
    const float* __restrict__ W1, const float* __restrict__ b1,
    const float* __restrict__ W2, const float* __restrict__ b2,
    float* __restrict__ out) {
  const int r = blockIdx.x, t = threadIdx.x;
  __shared__ float f[NCLS];
  __shared__ float hh[128];
  if (t < NCLS) f[t] = fused[r * NCLS + t];
  __syncthreads();
  float s = b1[t];
  #pragma unroll
  for (int k = 0; k < NCLS; ++k) s += f[k] * W1[k * 128 + t];
  hh[t] = s >= 0.f ? s : 0.25f * s;
  __syncthreads();
  if (t < NCLS) {
    float o = b2[t];
    for (int k = 0; k < 128; ++k) o += hh[k] * W2[k * NCLS + t];
    out[r * NCLS + t] = o;
  }
}

// ---------------------------------------------------------------------------
extern "C" void kernel_launch(void* const* d_in, const int* in_sizes, int n_in,
                              void* d_out, int out_size, void* d_ws, size_t ws_size,
                              hipStream_t stream) {
  const float* x[3]    = {(const float*)d_in[0], (const float*)d_in[1], (const float*)d_in[2]};
  const float* encW[3] = {(const float*)d_in[3], (const float*)d_in[4], (const float*)d_in[5]};
  const float* enc_b = (const float*)d_in[6];
  const float* bn_g  = (const float*)d_in[7];
  const float* bn_b  = (const float*)d_in[8];
  const float* gc1W  = (const float*)d_in[9];
  const float* gc1b  = (const float*)d_in[10];
  const float* gc2W  = (const float*)d_in[11];
  const float* gc2b  = (const float*)d_in[12];
  const float* clfW  = (const float*)d_in[13];
  const float* clfb  = (const float*)d_in[14];
  const float* attn  = (const float*)d_in[15];
  const float* f1W   = (const float*)d_in[16];
  const float* f1b   = (const float*)d_in[17];
  const float* f2W   = (const float*)d_in[18];
  const float* f2b   = (const float*)d_in[19];
  float* out = (float*)d_out;

  // Workspace layout
  float* ws = (float*)d_ws;
  float* A = ws;                           // 8192*256 feat / h1
  float* B = A + (size_t)NROWS * HID;      // 8192*256 fn / h2
  float* C = B + (size_t)NROWS * HID;      // 8192*256 gemm temp
  int*   nidx = (int*)(C + (size_t)NROWS * HID);       // 8192*10
  float* nval = (float*)(nidx + (size_t)NROWS * TOPK); // 8192*10
  float* dinv = nval + (size_t)NROWS * TOPK;           // 8192
  float* logits = dinv + NROWS;                        // 3*8192*5
  float* fused = logits + (size_t)3 * NROWS * NCLS;    // 8192*5
  ushort* Pb = (ushort*)(fused + (size_t)NROWS * NCLS); // 8192*512 bf16 limbs
  float* stripe = (float*)(Pb + (size_t)NROWS * KP);    // SR * 8192
  const size_t fixed_bytes = (size_t)((char*)stripe - (char*)ws);
  const size_t avail = (ws_size > fixed_bytes) ? (ws_size - fixed_bytes) : 0;
  int SR = 128;
  while (SR < NROWS && (size_t)SR * 2 * NROWS * sizeof(float) <= avail) SR <<= 1;

  const dim3 blk(256);
  for (int i = 0; i < 3; ++i) {
    const int D = in_sizes[i] / NROWS;
    // encoder: A = relu(x @ W + b)
    {
      dim3 g((HID + 63) / 64, (NROWS + 63) / 64);
      gemm_kernel<true, 1><<<g, blk, 0, stream>>>(x[i], encW[i], enc_b + i * HID,
                                                  A, NROWS, HID, D);
    }
    bn_kernel<<<HID, blk, 0, stream>>>(A, bn_g + i * HID, bn_b + i * HID);
    rownorm_kernel<<<NROWS, blk, 0, stream>>>(A, B);
    // two-limb bf16 pack of fn
    pack_kernel<<<NROWS * HID / 256, blk, 0, stream>>>(B, Pb);
    // sim stripes (MFMA) + per-row top-k with exact refinement
    for (int s0 = 0; s0 < NROWS; s0 += SR) {
      dim3 g(NROWS / TN, SR / TM);
      simgemm_kernel<<<g, blk, 0, stream>>>(Pb, stripe, s0);
      topk_kernel<<<SR / 4, blk, 0, stream>>>(stripe, s0, B, nidx, nval, dinv);
    }
    // gc1
    {
      dim3 g(HID / 64, NROWS / 64);
      gemm_kernel<false, 0><<<g, blk, 0, stream>>>(A, gc1W + (size_t)i * HID * HID,
                                                   nullptr, C, NROWS, HID, HID);
    }
    spmm_kernel<<<NROWS, blk, 0, stream>>>(C, nidx, nval, dinv, gc1b + i * HID, A);
    // gc2
    {
      dim3 g(HID / 64, NROWS / 64);
      gemm_kernel<false, 0><<<g, blk, 0, stream>>>(A, gc2W + (size_t)i * HID * HID,
                                                   nullptr, C, NROWS, HID, HID);
    }
    spmm_kernel<<<NROWS, blk, 0, stream>>>(C, nidx, nval, dinv, gc2b + i * HID, B);
    clf_kernel<<<(NROWS * NCLS + 255) / 256, blk, 0, stream>>>(B, clfW + (size_t)i * HID * NCLS,
                                                               clfb + i * NCLS,
                                                               logits + (size_t)i * NROWS * NCLS);
  }
  fuse_kernel<<<(NROWS * NCLS + 255) / 256, blk, 0, stream>>>(logits, attn, fused);
  head_kernel<<<NROWS, dim3(128), 0, stream>>>(fused, f1W, f1b, f2W, f2b, out);
}

// Round 6
// 1569.588 us; speedup vs baseline: 1.5219x; 1.0283x over previous
//
#include <hip/hip_runtime.h>
#include <cfloat>
#include <cstdint>
#include <cstddef>

#define NROWS 8192
#define HID 256
#define NCLS 5
#define TOPK 10
#define CBUF 192    // candidate buffer cap per row (typ. ~20-60 used)
#define TM 128
#define TN 128
#define BK 32
#define TM_L 128
#define TN_L 64

typedef __bf16 bf16x8 __attribute__((ext_vector_type(8)));
typedef float f32x4 __attribute__((ext_vector_type(4)));

__device__ inline ushort f2bf(float x) {
  unsigned u = __float_as_uint(x);
  unsigned r = (u + 0x7fffu + ((u >> 16) & 1u)) >> 16;  // RNE
  return (ushort)r;
}
__device__ inline float bf2f(ushort b) { return __uint_as_float(((unsigned)b) << 16); }

// async global->LDS 16B/lane; LDS dest is wave-uniform base + lane*16
__device__ __forceinline__ void load_lds16(const void* g, void* l) {
  __builtin_amdgcn_global_load_lds(
      (const __attribute__((address_space(1))) void*)g,
      (__attribute__((address_space(3))) void*)l, 16, 0, 0);
}

// ---------------------------------------------------------------------------
// Pack A rows (M x D fp32 -> hi/lo bf16 limb planes, K padded to Kp) and
// W (D x HID fp32, transposed -> HID x Kp limb planes) in one launch.
// ---------------------------------------------------------------------------
__global__ __launch_bounds__(256) void packAB_kernel(const float* __restrict__ X,
    const float* __restrict__ W, ushort* __restrict__ Ah, ushort* __restrict__ Al,
    ushort* __restrict__ Bh, ushort* __restrict__ Bl, int D, int Kp, int ksh) {
  const int id = blockIdx.x * 256 + threadIdx.x;
  const int atotal = NROWS << ksh;
  if (id < atotal) {
    const int r = id >> ksh, k = id & (Kp - 1);
    const float x = (k < D) ? X[(size_t)r * D + k] : 0.f;
    const ushort h = f2bf(x);
    Ah[id] = h;
    Al[id] = f2bf(x - bf2f(h));
  } else {
    const int id2 = id - atotal;
    if (id2 < (HID << ksh)) {
      const int n = id2 >> ksh, k = id2 & (Kp - 1);
      const float x = (k < D) ? W[(size_t)k * HID + n] : 0.f;
      const ushort h = f2bf(x);
      Bh[id2] = h;
      Bl[id2] = f2bf(x - bf2f(h));
    }
  }
}

// ---------------------------------------------------------------------------
// Two-limb (fp32-grade) bf16 MFMA GEMM: C[M=NROWS x HID] = act(A @ B^T + bias)
// A limbs: [NROWS x Kp], B limbs (pre-transposed weights): [HID x Kp].
// 4 segments: (h,h),(h,l),(l,h),(l,l) accumulate into the same fp32 acc.
// Tile 128x64, 4 waves (2x2), wave 64x32 = 4x2 frags of 16x16x32.
// ---------------------------------------------------------------------------
template<bool BIAS, int ACT>
__global__ __launch_bounds__(256) void limbgemm_kernel(const ushort* __restrict__ Ah,
    const ushort* __restrict__ Al, const ushort* __restrict__ Bh,
    const ushort* __restrict__ Bl, const float* __restrict__ bias,
    float* __restrict__ C, int Kp) {
  __shared__ ushort As[TM_L * BK];
  __shared__ ushort Bs[TN_L * BK];
  const int tid = threadIdx.x;
  const int wave = tid >> 6, lane = tid & 63;
  const int bm = blockIdx.y * TM_L;
  const int bn = blockIdx.x * TN_L;
  const int wr = (wave >> 1) * 64;
  const int wc = (wave & 1) * 32;

  f32x4 acc[4][2];
  const f32x4 zero = {0.f, 0.f, 0.f, 0.f};
  #pragma unroll
  for (int i = 0; i < 4; ++i) { acc[i][0] = zero; acc[i][1] = zero; }

  const int p0 = tid, p1 = tid + 256;
  const int r0 = p0 >> 2, kl0 = (p0 & 3) ^ ((r0 & 3) ^ ((r0 >> 2) & 1));
  const int r1 = p1 >> 2, kl1 = (p1 & 3) ^ ((r1 & 3) ^ ((r1 >> 2) & 1));
  const int rB = tid >> 2, klB = (tid & 3) ^ ((rB & 3) ^ ((rB >> 2) & 1));
  const size_t aoff0 = (size_t)(bm + r0) * Kp + kl0 * 8;
  const size_t aoff1 = (size_t)(bm + r1) * Kp + kl1 * 8;
  const size_t boff  = (size_t)(bn + rB) * Kp + klB * 8;

  for (int s = 0; s < 4; ++s) {
    const ushort* Ap = (s < 2) ? Ah : Al;
    const ushort* Bp = (s & 1) ? Bl : Bh;
    for (int k0 = 0; k0 < Kp; k0 += BK) {
      __syncthreads();
      load_lds16(Ap + aoff0 + k0, &As[p0 * 8]);
      load_lds16(Ap + aoff1 + k0, &As[p1 * 8]);
      load_lds16(Bp + boff + k0, &Bs[tid * 8]);
      __syncthreads();
      bf16x8 af[4], bf[2];
      const int kg = lane >> 4;
      #pragma unroll
      for (int f = 0; f < 4; ++f) {
        const int m = wr + f * 16 + (lane & 15);
        const int sa = m * 4 + (kg ^ (m & 3) ^ ((m >> 2) & 1));
        af[f] = *(const bf16x8*)&As[sa * 8];
      }
      #pragma unroll
      for (int f = 0; f < 2; ++f) {
        const int n = wc + f * 16 + (lane & 15);
        const int sb = n * 4 + (kg ^ (n & 3) ^ ((n >> 2) & 1));
        bf[f] = *(const bf16x8*)&Bs[sb * 8];
      }
      #pragma unroll
      for (int fr = 0; fr < 4; ++fr)
        #pragma unroll
        for (int fc = 0; fc < 2; ++fc)
          acc[fr][fc] = __builtin_amdgcn_mfma_f32_16x16x32_bf16(af[fr], bf[fc], acc[fr][fc], 0, 0, 0);
    }
  }
  const int cq = lane >> 4, cc = lane & 15;
  #pragma unroll
  for (int fr = 0; fr < 4; ++fr) {
    #pragma unroll
    for (int fc = 0; fc < 2; ++fc) {
      const int rb = bm + wr + fr * 16 + cq * 4;
      const int col = bn + wc + fc * 16 + cc;
      const float bb = BIAS ? bias[col] : 0.f;
      float* cp = C + (size_t)rb * HID + col;
      #pragma unroll
      for (int e = 0; e < 4; ++e) {
        float v = acc[fr][fc][e] + bb;
        if (ACT == 1) v = fmaxf(v, 0.f);
        cp[(size_t)e * HID] = v;
      }
    }
  }
}

// ---------------------------------------------------------------------------
// BatchNorm1d (training stats, biased var, eps=1e-5), in place.
// ---------------------------------------------------------------------------
__global__ __launch_bounds__(256) void bn_kernel(float* __restrict__ F,
    const float* __restrict__ g, const float* __restrict__ b) {
  const int j = blockIdx.x, t = threadIdx.x;
  float s = 0.f, s2 = 0.f;
  for (int r = t; r < NROWS; r += 256) {
    float v = F[(size_t)r * HID + j];
    s += v; s2 += v * v;
  }
  __shared__ float sh1[256];
  __shared__ float sh2[256];
  sh1[t] = s; sh2[t] = s2;
  __syncthreads();
  for (int st = 128; st > 0; st >>= 1) {
    if (t < st) { sh1[t] += sh1[t + st]; sh2[t] += sh2[t + st]; }
    __syncthreads();
  }
  const float mu = sh1[0] / (float)NROWS;
  const float var = sh2[0] / (float)NROWS - mu * mu;
  const float rstd = rsqrtf(var + 1e-5f);
  const float gg = g[j], bb = b[j];
  for (int r = t; r < NROWS; r += 256) {
    const size_t o = (size_t)r * HID + j;
    F[o] = (F[o] - mu) * rstd * gg + bb;
  }
}

// ---------------------------------------------------------------------------
// L2 row-normalize fn = feat/||feat|| and emit hi-limb bf16 plane for sim.
// ---------------------------------------------------------------------------
__global__ __launch_bounds__(256) void rownorm_kernel(const float* __restrict__ F,
    float* __restrict__ FN, ushort* __restrict__ Ph) {
  const int r = blockIdx.x, t = threadIdx.x;
  const float v = F[(size_t)r * HID + t];
  __shared__ float sh[256];
  sh[t] = v * v;
  __syncthreads();
  for (int st = 128; st > 0; st >>= 1) {
    if (t < st) sh[t] += sh[t + st];
    __syncthreads();
  }
  const float inv = 1.0f / fmaxf(sqrtf(sh[0]), 1e-12f);
  const float fn = v * inv;
  FN[(size_t)r * HID + t] = fn;
  Ph[(size_t)r * HID + t] = f2bf(fn);
}

// ---------------------------------------------------------------------------
// sim stripe = Ph[mbase+..] @ Ph^T via bf16 MFMA 16x16x32, K=256 (hi-limb
// only; exact refinement fixes ranking). 128x128 tile, 4 waves, BK=32,
// XOR-swizzled LDS, global_load_lds width-16 staging.
// ---------------------------------------------------------------------------
__global__ __launch_bounds__(256) void simgemm_kernel(const ushort* __restrict__ P,
    float* __restrict__ C, int mbase) {
  __shared__ ushort As[TM * BK];
  __shared__ ushort Bs[TN * BK];
  const int tid = threadIdx.x;
  const int wave = tid >> 6, lane = tid & 63;
  const int bmr = blockIdx.y * TM;
  const int bm = mbase + bmr;
  const int bn = blockIdx.x * TN;
  const int wr = (wave >> 1) * 64;
  const int wc = (wave & 1) * 64;

  f32x4 acc[4][4];
  const f32x4 zero = {0.f, 0.f, 0.f, 0.f};
  #pragma unroll
  for (int i = 0; i < 4; ++i)
    #pragma unroll
    for (int j = 0; j < 4; ++j) acc[i][j] = zero;

  const int p0 = tid, p1 = tid + 256;
  const int r0 = p0 >> 2, kl0 = (p0 & 3) ^ ((r0 & 3) ^ ((r0 >> 2) & 1));
  const int r1 = p1 >> 2, kl1 = (p1 & 3) ^ ((r1 & 3) ^ ((r1 >> 2) & 1));
  const ushort* pa0 = P + (size_t)(bm + r0) * HID + kl0 * 8;
  const ushort* pa1 = P + (size_t)(bm + r1) * HID + kl1 * 8;
  const ushort* pb0 = P + (size_t)(bn + r0) * HID + kl0 * 8;
  const ushort* pb1 = P + (size_t)(bn + r1) * HID + kl1 * 8;

  for (int k0 = 0; k0 < HID; k0 += BK) {
    __syncthreads();
    load_lds16(pa0 + k0, &As[p0 * 8]);
    load_lds16(pa1 + k0, &As[p1 * 8]);
    load_lds16(pb0 + k0, &Bs[p0 * 8]);
    load_lds16(pb1 + k0, &Bs[p1 * 8]);
    __syncthreads();
    bf16x8 af[4], bf[4];
    const int kg = lane >> 4;
    #pragma unroll
    for (int f = 0; f < 4; ++f) {
      const int m = wr + f * 16 + (lane & 15);
      const int sa = m * 4 + (kg ^ (m & 3) ^ ((m >> 2) & 1));
      af[f] = *(const bf16x8*)&As[sa * 8];
      const int n = wc + f * 16 + (lane & 15);
      const int sb = n * 4 + (kg ^ (n & 3) ^ ((n >> 2) & 1));
      bf[f] = *(const bf16x8*)&Bs[sb * 8];
    }
    #pragma unroll
    for (int fr = 0; fr < 4; ++fr)
      #pragma unroll
      for (int fc = 0; fc < 4; ++fc)
        acc[fr][fc] = __builtin_amdgcn_mfma_f32_16x16x32_bf16(af[fr], bf[fc], acc[fr][fc], 0, 0, 0);
  }
  const int cq = lane >> 4, cc = lane & 15;
  #pragma unroll
  for (int fr = 0; fr < 4; ++fr) {
    #pragma unroll
    for (int fc = 0; fc < 4; ++fc) {
      const int rb = bmr + wr + fr * 16 + cq * 4;
      const int col = bn + wc + fc * 16 + cc;
      float* cp = C + (size_t)rb * NROWS + col;
      cp[0] = acc[fr][fc].x;
      cp[(size_t)1 * NROWS] = acc[fr][fc].y;
      cp[(size_t)2 * NROWS] = acc[fr][fc].z;
      cp[(size_t)3 * NROWS] = acc[fr][fc].w;
    }
  }
}

// ---------------------------------------------------------------------------
// Threshold-based per-row top-K (one wave/row): pass A lane-max -> tau =
// 16th largest lane max; pass B compacts x>=tau (L3-hot reread); exact fp32
// dots for all candidates; exact top-10.
// ---------------------------------------------------------------------------
__global__ __launch_bounds__(256) void topk_kernel(const float* __restrict__ S, int base,
    const float* __restrict__ FN, int* __restrict__ nidx, float* __restrict__ nval,
    float* __restrict__ dinv) {
  const int wave = threadIdx.x >> 6, lane = threadIdx.x & 63;
  const int lr = blockIdx.x * 4 + wave;
  const int row = base + lr;
  const float4* rowp = (const float4*)(S + (size_t)lr * NROWS);

  // Pass A: per-lane max, self masked
  float m = -FLT_MAX;
  for (int it = 0; it < 32; ++it) {
    const float4 q = rowp[it * 64 + lane];
    const int j0 = (it * 64 + lane) * 4;
    m = fmaxf(m, (j0 + 0 == row) ? -FLT_MAX : q.x);
    m = fmaxf(m, (j0 + 1 == row) ? -FLT_MAX : q.y);
    m = fmaxf(m, (j0 + 2 == row) ? -FLT_MAX : q.z);
    m = fmaxf(m, (j0 + 3 == row) ? -FLT_MAX : q.w);
  }
  float tau = m;
  {
    float cur = m;
    #pragma unroll
    for (int sel = 0; sel < 16; ++sel) {
      float bv = cur;
      int bl = lane;
      #pragma unroll
      for (int s = 1; s < 64; s <<= 1) {
        const float ov = __shfl_xor(bv, s);
        const int ol = __shfl_xor(bl, s);
        if (ov > bv || (ov == bv && ol < bl)) { bv = ov; bl = ol; }
      }
      tau = bv;
      if (lane == bl) cur = -FLT_MAX;
    }
  }

  // Pass B: compact candidates >= tau
  __shared__ int ccnt[4];
  __shared__ int cbi[4][CBUF];
  __shared__ float fnrow[4][HID];
  __shared__ float ev[4][CBUF];
  if (lane == 0) ccnt[wave] = 0;
  ((float4*)fnrow[wave])[lane] = ((const float4*)(FN + (size_t)row * HID))[lane];
  __syncthreads();
  for (int it = 0; it < 32; ++it) {
    const float4 q = rowp[it * 64 + lane];
    const int j0 = (it * 64 + lane) * 4;
    const float xs[4] = {q.x, q.y, q.z, q.w};
    #pragma unroll
    for (int e = 0; e < 4; ++e) {
      const int j = j0 + e;
      const float x = (j == row) ? -FLT_MAX : xs[e];
      if (x >= tau) {
        const int pos = atomicAdd(&ccnt[wave], 1);
        if (pos < CBUF) cbi[wave][pos] = j;
      }
    }
  }
  __syncthreads();
  const int cnt = min(ccnt[wave], CBUF);

  // exact fp32 refinement (4 lanes per candidate)
  const int c = lane >> 2, q4 = lane & 3;
  for (int b0 = 0; b0 < cnt; b0 += 16) {
    const int ci = b0 + c;
    const int cand = (ci < cnt) ? cbi[wave][ci] : 0;
    float s = 0.f;
    const float* fc = FN + (size_t)cand * HID + q4 * 64;
    const float* fr = fnrow[wave] + q4 * 64;
    #pragma unroll 8
    for (int k = 0; k < 64; ++k) s += fr[k] * fc[k];
    s += __shfl_xor(s, 1);
    s += __shfl_xor(s, 2);
    if (q4 == 0 && ci < cnt) ev[wave][ci] = s;
  }
  __syncthreads();

  // exact top-10 selection
  float outv[TOPK];
  int outi[TOPK];
  float sum = 1.0f;  // diag contributes 1
  #pragma unroll
  for (int sel = 0; sel < TOPK; ++sel) {
    float bv = -FLT_MAX;
    int bp = 0;
    if (lane < cnt) { bv = ev[wave][lane]; bp = lane; }
    if (lane + 64 < cnt) {
      const float v2 = ev[wave][lane + 64];
      if (v2 > bv) { bv = v2; bp = lane + 64; }
    }
    if (lane + 128 < cnt) {
      const float v3 = ev[wave][lane + 128];
      if (v3 > bv) { bv = v3; bp = lane + 128; }
    }
    #pragma unroll
    for (int s = 1; s < 64; s <<= 1) {
      const float ov = __shfl_xor(bv, s);
      const int op = __shfl_xor(bp, s);
      if (ov > bv || (ov == bv && op < bp)) { bv = ov; bp = op; }
    }
    outv[sel] = bv;
    outi[sel] = bp;
    sum += fabsf(bv);
    if (lane == 0) ev[wave][bp] = -FLT_MAX;
  }
  if (lane == 0) {
    const float inv = 1.0f / fmaxf(sum, 1e-12f);
    dinv[row] = inv;
    #pragma unroll
    for (int sel = 0; sel < TOPK; ++sel) {
      nval[row * TOPK + sel] = outv[sel] * inv;
      nidx[row * TOPK + sel] = cbi[wave][outi[sel]];
    }
  }
}

// ---------------------------------------------------------------------------
// Sparse adj (11 nnz/row) @ T + bias, leaky_relu(0.25).
// ---------------------------------------------------------------------------
__global__ __launch_bounds__(256) void spmm_kernel(const float* __restrict__ T,
    const int* __restrict__ nidx, const float* __restrict__ nval,
    const float* __restrict__ dinv, const float* __restrict__ bias,
    float* __restrict__ H) {
  const int r = blockIdx.x, c = threadIdx.x;
  float acc = dinv[r] * T[(size_t)r * HID + c];
  #pragma unroll
  for (int n = 0; n < TOPK; ++n) {
    acc += nval[r * TOPK + n] * T[(size_t)nidx[r * TOPK + n] * HID + c];
  }
  acc += bias[c];
  H[(size_t)r * HID + c] = acc >= 0.f ? acc : 0.25f * acc;
}

__global__ __launch_bounds__(256) void clf_kernel(const float* __restrict__ H,
    const float* __restrict__ W, const float* __restrict__ b,
    float* __restrict__ L) {
  const int id = blockIdx.x * 256 + threadIdx.x;
  if (id >= NROWS * NCLS) return;
  const int r = id / NCLS, c = id % NCLS;
  float s = b[c];
  const float* hr = H + (size_t)r * HID;
  for (int k = 0; k < HID; ++k) s += hr[k] * W[k * NCLS + c];
  L[id] = s;
}

__global__ __launch_bounds__(256) void fuse_kernel(const float* __restrict__ L,
    const float* __restrict__ attn, float* __restrict__ fused) {
  const int id = blockIdx.x * 256 + threadIdx.x;
  if (id >= NROWS * NCLS) return;
  const float a0 = attn[0], a1 = attn[1], a2 = attn[2];
  const float m = fmaxf(a0, fmaxf(a1, a2));
  const float e0 = expf(a0 - m), e1 = expf(a1 - m), e2 = expf(a2 - m);
  const float inv = 1.0f / (e0 + e1 + e2);
  const float l0 = L[id];
  const float l1 = L[NROWS * NCLS + id];
  const float l2 = L[2 * NROWS * NCLS + id];
  const float s0 = 1.0f / (1.0f + expf(-l0));
  const float s1 = 1.0f / (1.0f + expf(-l1));
  const float s2 = 1.0f / (1.0f + expf(-l2));
  fused[id] = (e0 * s0 + e1 * s1 + e2 * s2) * inv;
}

__global__ __launch_bounds__(128) void head_kernel(const float* __restrict__ fused,
    const float* __restrict__ W1, const float* __restrict__ b1,
    const float* __restrict__ W2, const float* __restrict__ b2,
    float* __restrict__ out) {
  const int r = blockIdx.x, t = threadIdx.x;
  __shared__ float f[NCLS];
  __shared__ float hh[128];
  if (t < NCLS) f[t] = fused[r * NCLS + t];
  __syncthreads();
  float s = b1[t];
  #pragma unroll
  for (int k = 0; k < NCLS; ++k) s += f[k] * W1[k * 128 + t];
  hh[t] = s >= 0.f ? s : 0.25f * s;
  __syncthreads();
  if (t < NCLS) {
    float o = b2[t];
    for (int k = 0; k < 128; ++k) o += hh[k] * W2[k * NCLS + t];
    out[r * NCLS + t] = o;
  }
}

// ---------------------------------------------------------------------------
extern "C" void kernel_launch(void* const* d_in, const int* in_sizes, int n_in,
                              void* d_out, int out_size, void* d_ws, size_t ws_size,
                              hipStream_t stream) {
  const float* x[3]    = {(const float*)d_in[0], (const float*)d_in[1], (const float*)d_in[2]};
  const float* encW[3] = {(const float*)d_in[3], (const float*)d_in[4], (const float*)d_in[5]};
  const float* enc_b = (const float*)d_in[6];
  const float* bn_g  = (const float*)d_in[7];
  const float* bn_b  = (const float*)d_in[8];
  const float* gc1W  = (const float*)d_in[9];
  const float* gc1b  = (const float*)d_in[10];
  const float* gc2W  = (const float*)d_in[11];
  const float* gc2b  = (const float*)d_in[12];
  const float* clfW  = (const float*)d_in[13];
  const float* clfb  = (const float*)d_in[14];
  const float* attn  = (const float*)d_in[15];
  const float* f1W   = (const float*)d_in[16];
  const float* f1b   = (const float*)d_in[17];
  const float* f2W   = (const float*)d_in[18];
  const float* f2b   = (const float*)d_in[19];
  float* out = (float*)d_out;

  // Workspace layout
  const size_t NH = (size_t)NROWS * HID;           // 2M elems
  float* ws = (float*)d_ws;
  float* A = ws;                                   // feat / h1
  float* B = A + NH;                               // fn / h2
  float* C = B + NH;                               // gemm temp
  int*   nidx = (int*)(C + NH);                    // 8192*10
  float* nval = (float*)(nidx + (size_t)NROWS * TOPK);
  float* dinv = nval + (size_t)NROWS * TOPK;
  float* logits = dinv + NROWS;                    // 3*8192*5
  float* fused = logits + (size_t)3 * NROWS * NCLS;
  ushort* Ph = (ushort*)(fused + (size_t)NROWS * NCLS);  // hi-limb fn, 2M
  ushort* Ah = Ph + NH;                            // 8192*1024
  ushort* Al = Ah + (size_t)NROWS * 1024;
  ushort* Bh = Al + (size_t)NROWS * 1024;          // 256*1024
  ushort* Bl = Bh + (size_t)HID * 1024;
  float* stripe = (float*)(Bl + (size_t)HID * 1024);
  const size_t fixed_bytes = (size_t)((char*)stripe - (char*)ws);
  const size_t avail = (ws_size > fixed_bytes) ? (ws_size - fixed_bytes) : 0;
  int SR = 2048;  // 64 MB stripe -> L3-resident
  while (SR > 256 && (size_t)SR * NROWS * sizeof(float) > avail) SR >>= 1;

  const dim3 blk(256);
  for (int i = 0; i < 3; ++i) {
    const int D = in_sizes[i] / NROWS;
    int Kp = 256, ksh = 8;
    while (Kp < D) { Kp <<= 1; ksh++; }
    // encoder: pack limbs of x and W^T, then A = relu(x @ W + b)
    packAB_kernel<<<((NROWS + HID) << ksh) / 256, blk, 0, stream>>>(
        x[i], encW[i], Ah, Al, Bh, Bl, D, Kp, ksh);
    limbgemm_kernel<true, 1><<<dim3(HID / TN_L, NROWS / TM_L), blk, 0, stream>>>(
        Ah, Al, Bh, Bl, enc_b + i * HID, A, Kp);
    bn_kernel<<<HID, blk, 0, stream>>>(A, bn_g + i * HID, bn_b + i * HID);
    rownorm_kernel<<<NROWS, blk, 0, stream>>>(A, B, Ph);
    // sim stripes (hi-limb MFMA, L3-resident) + per-row top-k (exact refine)
    for (int s0 = 0; s0 < NROWS; s0 += SR) {
      simgemm_kernel<<<dim3(NROWS / TN, SR / TM), blk, 0, stream>>>(Ph, stripe, s0);
      topk_kernel<<<SR / 4, blk, 0, stream>>>(stripe, s0, B, nidx, nval, dinv);
    }
    // gc1: C = feat @ W1 (two-limb MFMA), A = leaky(adj @ C + b1)
    packAB_kernel<<<((NROWS + HID) << 8) / 256, blk, 0, stream>>>(
        A, gc1W + (size_t)i * HID * HID, Ah, Al, Bh, Bl, HID, 256, 8);
    limbgemm_kernel<false, 0><<<dim3(HID / TN_L, NROWS / TM_L), blk, 0, stream>>>(
        Ah, Al, Bh, Bl, nullptr, C, 256);
    spmm_kernel<<<NROWS, blk, 0, stream>>>(C, nidx, nval, dinv, gc1b + i * HID, A);
    // gc2
    packAB_kernel<<<((NROWS + HID) << 8) / 256, blk, 0, stream>>>(
        A, gc2W + (size_t)i * HID * HID, Ah, Al, Bh, Bl, HID, 256, 8);
    limbgemm_kernel<false, 0><<<dim3(HID / TN_L, NROWS / TM_L), blk, 0, stream>>>(
        Ah, Al, Bh, Bl, nullptr, C, 256);
    spmm_kernel<<<NROWS, blk, 0, stream>>>(C, nidx, nval, dinv, gc2b + i * HID, B);
    clf_kernel<<<(NROWS * NCLS + 255) / 256, blk, 0, stream>>>(B, clfW + (size_t)i * HID * NCLS,
                                                               clfb + i * NCLS,
                                                               logits + (size_t)i * NROWS * NCLS);
  }
  fuse_kernel<<<(NROWS * NCLS + 255) / 256, blk, 0, stream>>>(logits, attn, fused);
  head_kernel<<<NROWS, dim3(128), 0, stream>>>(fused, f1W, f1b, f2W, f2b, out);
}

// Round 7
// 1290.702 us; speedup vs baseline: 1.8507x; 1.2161x over previous
//
#include <hip/hip_runtime.h>
#include <cfloat>
#include <cstdint>
#include <cstddef>

#define NROWS 8192
#define HID 256
#define NCLS 5
#define TOPK 10
#define CBUF 192    // candidate buffer cap per row (typ. ~20-60 used)
#define TM 128
#define TN 128
#define BK 32

typedef __bf16 bf16x8 __attribute__((ext_vector_type(8)));
typedef float f32x4 __attribute__((ext_vector_type(4)));

__device__ inline ushort f2bf(float x) {
  unsigned u = __float_as_uint(x);
  unsigned r = (u + 0x7fffu + ((u >> 16) & 1u)) >> 16;  // RNE
  return (ushort)r;
}
__device__ inline float bf2f(ushort b) { return __uint_as_float(((unsigned)b) << 16); }

// async global->LDS 16B/lane; LDS dest is wave-uniform base + lane*16
__device__ __forceinline__ void load_lds16(const void* g, void* l) {
  __builtin_amdgcn_global_load_lds(
      (const __attribute__((address_space(1))) void*)g,
      (__attribute__((address_space(3))) void*)l, 16, 0, 0);
}

// ---------------------------------------------------------------------------
// Encoder pack: X rows (M x D fp32 -> hi/lo bf16 limb planes, K padded to Kp)
// and W (D x HID fp32, transposed -> HID x Kp limb planes).
// ---------------------------------------------------------------------------
__global__ __launch_bounds__(256) void packAB_kernel(const float* __restrict__ X,
    const float* __restrict__ W, ushort* __restrict__ Ah, ushort* __restrict__ Al,
    ushort* __restrict__ Bh, ushort* __restrict__ Bl, int D, int Kp, int ksh) {
  const int id = blockIdx.x * 256 + threadIdx.x;
  const int atotal = NROWS << ksh;
  if (id < atotal) {
    const int r = id >> ksh, k = id & (Kp - 1);
    const float x = (k < D) ? X[(size_t)r * D + k] : 0.f;
    const ushort h = f2bf(x);
    Ah[id] = h;
    Al[id] = f2bf(x - bf2f(h));
  } else {
    const int id2 = id - atotal;
    if (id2 < (HID << ksh)) {
      const int n = id2 >> ksh, k = id2 & (Kp - 1);
      const float x = (k < D) ? W[(size_t)k * HID + n] : 0.f;
      const ushort h = f2bf(x);
      Bh[id2] = h;
      Bl[id2] = f2bf(x - bf2f(h));
    }
  }
}

// ---------------------------------------------------------------------------
// GCN weight pack: W [HID x HID] -> transposed limb planes [HID x 256].
// ---------------------------------------------------------------------------
__global__ __launch_bounds__(256) void packW_kernel(const float* __restrict__ W,
    ushort* __restrict__ Bh, ushort* __restrict__ Bl) {
  const int id = blockIdx.x * 256 + threadIdx.x;  // 65536
  const int k = id >> 8, n = id & 255;            // coalesced read over n
  const float x = W[(size_t)k * HID + n];
  const ushort h = f2bf(x);
  Bh[(size_t)n * HID + k] = h;
  Bl[(size_t)n * HID + k] = f2bf(x - bf2f(h));
}

// ---------------------------------------------------------------------------
// 3-segment two-limb bf16 MFMA GEMM: C[NROWS x HID] = act(A @ B^T + bias).
// Segments hh + hl + lh (ll ~2^-18, dropped). All 4 limb planes staged per
// K-step so each plane is read ONCE per block. 64x64 tile, 4 waves (2x2),
// wave 32x32 = 2x2 frags. 1-D grid with XCD swizzle: the 4 col-blocks of a
// row-block map to the same XCD adjacent in dispatch -> A re-reads hit L2.
// ---------------------------------------------------------------------------
template<bool BIAS, int ACT>
__global__ __launch_bounds__(256) void limbgemm_kernel(const ushort* __restrict__ Ah,
    const ushort* __restrict__ Al, const ushort* __restrict__ Bh,
    const ushort* __restrict__ Bl, const float* __restrict__ bias,
    float* __restrict__ C, int Kp) {
  __shared__ ushort AsH[64 * BK], AsL[64 * BK], BsH[64 * BK], BsL[64 * BK];
  const int tid = threadIdx.x;
  const int wave = tid >> 6, lane = tid & 63;
  // XCD swizzle: 512 blocks; xcd = bid&7 owns 16 row-blocks x 4 col-blocks
  const int bid = blockIdx.x;
  const int xcd = bid & 7, slot = bid >> 3;
  const int bxi = slot & 3;
  const int byi = xcd * 16 + (slot >> 2);
  const int bm = byi * 64, bn = bxi * 64;
  const int wr = (wave >> 1) * 32, wc = (wave & 1) * 32;

  f32x4 acc[2][2];
  const f32x4 zero = {0.f, 0.f, 0.f, 0.f};
  acc[0][0] = zero; acc[0][1] = zero; acc[1][0] = zero; acc[1][1] = zero;

  const int r0 = tid >> 2, kl0 = (tid & 3) ^ ((r0 & 3) ^ ((r0 >> 2) & 1));
  const size_t aoff = (size_t)(bm + r0) * Kp + kl0 * 8;
  const size_t boff = (size_t)(bn + r0) * Kp + kl0 * 8;

  for (int k0 = 0; k0 < Kp; k0 += BK) {
    __syncthreads();
    load_lds16(Ah + aoff + k0, &AsH[tid * 8]);
    load_lds16(Al + aoff + k0, &AsL[tid * 8]);
    load_lds16(Bh + boff + k0, &BsH[tid * 8]);
    load_lds16(Bl + boff + k0, &BsL[tid * 8]);
    __syncthreads();
    bf16x8 ah[2], al[2], bh[2], bl[2];
    const int kg = lane >> 4;
    #pragma unroll
    for (int f = 0; f < 2; ++f) {
      const int m = wr + f * 16 + (lane & 15);
      const int sa = m * 4 + (kg ^ (m & 3) ^ ((m >> 2) & 1));
      ah[f] = *(const bf16x8*)&AsH[sa * 8];
      al[f] = *(const bf16x8*)&AsL[sa * 8];
      const int n = wc + f * 16 + (lane & 15);
      const int sb = n * 4 + (kg ^ (n & 3) ^ ((n >> 2) & 1));
      bh[f] = *(const bf16x8*)&BsH[sb * 8];
      bl[f] = *(const bf16x8*)&BsL[sb * 8];
    }
    #pragma unroll
    for (int fr = 0; fr < 2; ++fr)
      #pragma unroll
      for (int fc = 0; fc < 2; ++fc) {
        acc[fr][fc] = __builtin_amdgcn_mfma_f32_16x16x32_bf16(ah[fr], bh[fc], acc[fr][fc], 0, 0, 0);
        acc[fr][fc] = __builtin_amdgcn_mfma_f32_16x16x32_bf16(ah[fr], bl[fc], acc[fr][fc], 0, 0, 0);
        acc[fr][fc] = __builtin_amdgcn_mfma_f32_16x16x32_bf16(al[fr], bh[fc], acc[fr][fc], 0, 0, 0);
      }
  }
  const int cq = lane >> 4, cc = lane & 15;
  #pragma unroll
  for (int fr = 0; fr < 2; ++fr) {
    #pragma unroll
    for (int fc = 0; fc < 2; ++fc) {
      const int rb = bm + wr + fr * 16 + cq * 4;
      const int col = bn + wc + fc * 16 + cc;
      const float bb = BIAS ? bias[col] : 0.f;
      float* cp = C + (size_t)rb * HID + col;
      #pragma unroll
      for (int e = 0; e < 4; ++e) {
        float v = acc[fr][fc][e] + bb;
        if (ACT == 1) v = fmaxf(v, 0.f);
        cp[(size_t)e * HID] = v;
      }
    }
  }
}

// ---------------------------------------------------------------------------
// Coalesced BatchNorm, 3 stages. stats: 64 blocks x 128 rows, thread=column.
// ---------------------------------------------------------------------------
__global__ __launch_bounds__(256) void bn_stats_kernel(const float* __restrict__ F,
    float* __restrict__ ps, float* __restrict__ ps2) {
  const int b = blockIdx.x, t = threadIdx.x;
  float s = 0.f, s2 = 0.f;
  const float* p = F + (size_t)b * 128 * HID + t;
  for (int r = 0; r < 128; ++r) {
    const float v = p[(size_t)r * HID];
    s += v; s2 += v * v;
  }
  ps[b * HID + t] = s;
  ps2[b * HID + t] = s2;
}

__global__ __launch_bounds__(256) void bn_finalize_kernel(const float* __restrict__ ps,
    const float* __restrict__ ps2, const float* __restrict__ g,
    const float* __restrict__ b, float* __restrict__ scale, float* __restrict__ shift) {
  const int t = threadIdx.x;
  float s = 0.f, s2 = 0.f;
  for (int i = 0; i < 64; ++i) { s += ps[i * HID + t]; s2 += ps2[i * HID + t]; }
  const float mu = s / (float)NROWS;
  const float var = s2 / (float)NROWS - mu * mu;
  const float rstd = rsqrtf(var + 1e-5f);
  const float sc = rstd * g[t];
  scale[t] = sc;
  shift[t] = b[t] - mu * sc;
}

// ---------------------------------------------------------------------------
// Fused bn-apply + L2 rownorm. One block per row. Emits:
//   FN  (fp32 normalized features, for exact top-k refinement)
//   Ph  (hi-limb bf16 of fn, for sim MFMA)
//   Fh/Fl (two-limb bf16 of bn'd feat, A-side of gc1 limbgemm)
// ---------------------------------------------------------------------------
__global__ __launch_bounds__(256) void bn_rownorm_kernel(const float* __restrict__ F,
    const float* __restrict__ scale, const float* __restrict__ shift,
    float* __restrict__ FN, ushort* __restrict__ Ph,
    ushort* __restrict__ Fh, ushort* __restrict__ Fl) {
  const int r = blockIdx.x, t = threadIdx.x;
  const float f = F[(size_t)r * HID + t] * scale[t] + shift[t];
  __shared__ float sh[256];
  sh[t] = f * f;
  __syncthreads();
  for (int st = 128; st > 0; st >>= 1) {
    if (t < st) sh[t] += sh[t + st];
    __syncthreads();
  }
  const float inv = 1.0f / fmaxf(sqrtf(sh[0]), 1e-12f);
  const float fn = f * inv;
  const size_t o = (size_t)r * HID + t;
  FN[o] = fn;
  Ph[o] = f2bf(fn);
  const ushort h = f2bf(f);
  Fh[o] = h;
  Fl[o] = f2bf(f - bf2f(h));
}

// ---------------------------------------------------------------------------
// sim stripe = Ph[mbase+..] @ Ph^T via bf16 MFMA 16x16x32, K=256 (hi-limb
// only; exact refinement fixes ranking). 128x128 tile, 4 waves, BK=32.
// ---------------------------------------------------------------------------
__global__ __launch_bounds__(256) void simgemm_kernel(const ushort* __restrict__ P,
    float* __restrict__ C, int mbase) {
  __shared__ ushort As[TM * BK];
  __shared__ ushort Bs[TN * BK];
  const int tid = threadIdx.x;
  const int wave = tid >> 6, lane = tid & 63;
  const int bmr = blockIdx.y * TM;
  const int bm = mbase + bmr;
  const int bn = blockIdx.x * TN;
  const int wr = (wave >> 1) * 64;
  const int wc = (wave & 1) * 64;

  f32x4 acc[4][4];
  const f32x4 zero = {0.f, 0.f, 0.f, 0.f};
  #pragma unroll
  for (int i = 0; i < 4; ++i)
    #pragma unroll
    for (int j = 0; j < 4; ++j) acc[i][j] = zero;

  const int p0 = tid, p1 = tid + 256;
  const int r0 = p0 >> 2, kl0 = (p0 & 3) ^ ((r0 & 3) ^ ((r0 >> 2) & 1));
  const int r1 = p1 >> 2, kl1 = (p1 & 3) ^ ((r1 & 3) ^ ((r1 >> 2) & 1));
  const ushort* pa0 = P + (size_t)(bm + r0) * HID + kl0 * 8;
  const ushort* pa1 = P + (size_t)(bm + r1) * HID + kl1 * 8;
  const ushort* pb0 = P + (size_t)(bn + r0) * HID + kl0 * 8;
  const ushort* pb1 = P + (size_t)(bn + r1) * HID + kl1 * 8;

  for (int k0 = 0; k0 < HID; k0 += BK) {
    __syncthreads();
    load_lds16(pa0 + k0, &As[p0 * 8]);
    load_lds16(pa1 + k0, &As[p1 * 8]);
    load_lds16(pb0 + k0, &Bs[p0 * 8]);
    load_lds16(pb1 + k0, &Bs[p1 * 8]);
    __syncthreads();
    bf16x8 af[4], bf[4];
    const int kg = lane >> 4;
    #pragma unroll
    for (int f = 0; f < 4; ++f) {
      const int m = wr + f * 16 + (lane & 15);
      const int sa = m * 4 + (kg ^ (m & 3) ^ ((m >> 2) & 1));
      af[f] = *(const bf16x8*)&As[sa * 8];
      const int n = wc + f * 16 + (lane & 15);
      const int sb = n * 4 + (kg ^ (n & 3) ^ ((n >> 2) & 1));
      bf[f] = *(const bf16x8*)&Bs[sb * 8];
    }
    #pragma unroll
    for (int fr = 0; fr < 4; ++fr)
      #pragma unroll
      for (int fc = 0; fc < 4; ++fc)
        acc[fr][fc] = __builtin_amdgcn_mfma_f32_16x16x32_bf16(af[fr], bf[fc], acc[fr][fc], 0, 0, 0);
  }
  const int cq = lane >> 4, cc = lane & 15;
  #pragma unroll
  for (int fr = 0; fr < 4; ++fr) {
    #pragma unroll
    for (int fc = 0; fc < 4; ++fc) {
      const int rb = bmr + wr + fr * 16 + cq * 4;
      const int col = bn + wc + fc * 16 + cc;
      float* cp = C + (size_t)rb * NROWS + col;
      cp[0] = acc[fr][fc].x;
      cp[(size_t)1 * NROWS] = acc[fr][fc].y;
      cp[(size_t)2 * NROWS] = acc[fr][fc].z;
      cp[(size_t)3 * NROWS] = acc[fr][fc].w;
    }
  }
}

// ---------------------------------------------------------------------------
// Threshold-based per-row top-K (one wave/row): pass A lane-max -> tau =
// 16th largest lane max; pass B compacts x>=tau (L3-hot reread); exact fp32
// dots for all candidates; exact top-10.
// ---------------------------------------------------------------------------
__global__ __launch_bounds__(256) void topk_kernel(const float* __restrict__ S, int base,
    const float* __restrict__ FN, int* __restrict__ nidx, float* __restrict__ nval,
    float* __restrict__ dinv) {
  const int wave = threadIdx.x >> 6, lane = threadIdx.x & 63;
  const int lr = blockIdx.x * 4 + wave;
  const int row = base + lr;
  const float4* rowp = (const float4*)(S + (size_t)lr * NROWS);

  // Pass A: per-lane max, self masked
  float m = -FLT_MAX;
  for (int it = 0; it < 32; ++it) {
    const float4 q = rowp[it * 64 + lane];
    const int j0 = (it * 64 + lane) * 4;
    m = fmaxf(m, (j0 + 0 == row) ? -FLT_MAX : q.x);
    m = fmaxf(m, (j0 + 1 == row) ? -FLT_MAX : q.y);
    m = fmaxf(m, (j0 + 2 == row) ? -FLT_MAX : q.z);
    m = fmaxf(m, (j0 + 3 == row) ? -FLT_MAX : q.w);
  }
  float tau = m;
  {
    float cur = m;
    #pragma unroll
    for (int sel = 0; sel < 16; ++sel) {
      float bv = cur;
      int bl = lane;
      #pragma unroll
      for (int s = 1; s < 64; s <<= 1) {
        const float ov = __shfl_xor(bv, s);
        const int ol = __shfl_xor(bl, s);
        if (ov > bv || (ov == bv && ol < bl)) { bv = ov; bl = ol; }
      }
      tau = bv;
      if (lane == bl) cur = -FLT_MAX;
    }
  }

  // Pass B: compact candidates >= tau
  __shared__ int ccnt[4];
  __shared__ int cbi[4][CBUF];
  __shared__ float fnrow[4][HID];
  __shared__ float ev[4][CBUF];
  if (lane == 0) ccnt[wave] = 0;
  ((float4*)fnrow[wave])[lane] = ((const float4*)(FN + (size_t)row * HID))[lane];
  __syncthreads();
  for (int it = 0; it < 32; ++it) {
    const float4 q = rowp[it * 64 + lane];
    const int j0 = (it * 64 + lane) * 4;
    const float xs[4] = {q.x, q.y, q.z, q.w};
    #pragma unroll
    for (int e = 0; e < 4; ++e) {
      const int j = j0 + e;
      const float x = (j == row) ? -FLT_MAX : xs[e];
      if (x >= tau) {
        const int pos = atomicAdd(&ccnt[wave], 1);
        if (pos < CBUF) cbi[wave][pos] = j;
      }
    }
  }
  __syncthreads();
  const int cnt = min(ccnt[wave], CBUF);

  // exact fp32 refinement (4 lanes per candidate)
  const int c = lane >> 2, q4 = lane & 3;
  for (int b0 = 0; b0 < cnt; b0 += 16) {
    const int ci = b0 + c;
    const int cand = (ci < cnt) ? cbi[wave][ci] : 0;
    float s = 0.f;
    const float* fc = FN + (size_t)cand * HID + q4 * 64;
    const float* fr = fnrow[wave] + q4 * 64;
    #pragma unroll 8
    for (int k = 0; k < 64; ++k) s += fr[k] * fc[k];
    s += __shfl_xor(s, 1);
    s += __shfl_xor(s, 2);
    if (q4 == 0 && ci < cnt) ev[wave][ci] = s;
  }
  __syncthreads();

  // exact top-10 selection
  float outv[TOPK];
  int outi[TOPK];
  float sum = 1.0f;  // diag contributes 1
  #pragma unroll
  for (int sel = 0; sel < TOPK; ++sel) {
    float bv = -FLT_MAX;
    int bp = 0;
    if (lane < cnt) { bv = ev[wave][lane]; bp = lane; }
    if (lane + 64 < cnt) {
      const float v2 = ev[wave][lane + 64];
      if (v2 > bv) { bv = v2; bp = lane + 64; }
    }
    if (lane + 128 < cnt) {
      const float v3 = ev[wave][lane + 128];
      if (v3 > bv) { bv = v3; bp = lane + 128; }
    }
    #pragma unroll
    for (int s = 1; s < 64; s <<= 1) {
      const float ov = __shfl_xor(bv, s);
      const int op = __shfl_xor(bp, s);
      if (ov > bv || (ov == bv && op < bp)) { bv = ov; bp = op; }
    }
    outv[sel] = bv;
    outi[sel] = bp;
    sum += fabsf(bv);
    if (lane == 0) ev[wave][bp] = -FLT_MAX;
  }
  if (lane == 0) {
    const float inv = 1.0f / fmaxf(sum, 1e-12f);
    dinv[row] = inv;
    #pragma unroll
    for (int sel = 0; sel < TOPK; ++sel) {
      nval[row * TOPK + sel] = outv[sel] * inv;
      nidx[row * TOPK + sel] = cbi[wave][outi[sel]];
    }
  }
}

// ---------------------------------------------------------------------------
// Sparse adj (11 nnz/row) @ T + bias, leaky_relu(0.25).
// EMIT=0: write fp32 H. EMIT=1: write two-limb bf16 planes (next gemm's A).
// ---------------------------------------------------------------------------
template<int EMIT>
__global__ __launch_bounds__(256) void spmm_kernel(const float* __restrict__ T,
    const int* __restrict__ nidx, const float* __restrict__ nval,
    const float* __restrict__ dinv, const float* __restrict__ bias,
    float* __restrict__ H, ushort* __restrict__ Hh, ushort* __restrict__ Hl) {
  const int r = blockIdx.x, c = threadIdx.x;
  float acc = dinv[r] * T[(size_t)r * HID + c];
  #pragma unroll
  for (int n = 0; n < TOPK; ++n) {
    acc += nval[r * TOPK + n] * T[(size_t)nidx[r * TOPK + n] * HID + c];
  }
  acc += bias[c];
  const float v = acc >= 0.f ? acc : 0.25f * acc;
  const size_t o = (size_t)r * HID + c;
  if (EMIT == 0) {
    H[o] = v;
  } else {
    const ushort h = f2bf(v);
    Hh[o] = h;
    Hl[o] = f2bf(v - bf2f(h));
  }
}

__global__ __launch_bounds__(256) void clf_kernel(const float* __restrict__ H,
    const float* __restrict__ W, const float* __restrict__ b,
    float* __restrict__ L) {
  const int id = blockIdx.x * 256 + threadIdx.x;
  if (id >= NROWS * NCLS) return;
  const int r = id / NCLS, c = id % NCLS;
  float s = b[c];
  const float* hr = H + (size_t)r * HID;
  for (int k = 0; k < HID; ++k) s += hr[k] * W[k * NCLS + c];
  L[id] = s;
}

__global__ __launch_bounds__(256) void fuse_kernel(const float* __restrict__ L,
    const float* __restrict__ attn, float* __restrict__ fused) {
  const int id = blockIdx.x * 256 + threadIdx.x;
  if (id >= NROWS * NCLS) return;
  const float a0 = attn[0], a1 = attn[1], a2 = attn[2];
  const float m = fmaxf(a0, fmaxf(a1, a2));
  const float e0 = expf(a0 - m), e1 = expf(a1 - m), e2 = expf(a2 - m);
  const float inv = 1.0f / (e0 + e1 + e2);
  const float l0 = L[id];
  const float l1 = L[NROWS * NCLS + id];
  const float l2 = L[2 * NROWS * NCLS + id];
  const float s0 = 1.0f / (1.0f + expf(-l0));
  const float s1 = 1.0f / (1.0f + expf(-l1));
  const float s2 = 1.0f / (1.0f + expf(-l2));
  fused[id] = (e0 * s0 + e1 * s1 + e2 * s2) * inv;
}

__global__ __launch_bounds__(128) void head_kernel(const float* __restrict__ fused,
    const float* __restrict__ W1, const float* __restrict__ b1,
    const float* __restrict__ W2, const float* __restrict__ b2,
    float* __restrict__ out) {
  const int r = blockIdx.x, t = threadIdx.x;
  __shared__ float f[NCLS];
  __shared__ float hh[128];
  if (t < NCLS) f[t] = fused[r * NCLS + t];
  __syncthreads();
  float s = b1[t];
  #pragma unroll
  for (int k = 0; k < NCLS; ++k) s += f[k] * W1[k * 128 + t];
  hh[t] = s >= 0.f ? s : 0.25f * s;
  __syncthreads();
  if (t < NCLS) {
    float o = b2[t];
    for (int k = 0; k < 128; ++k) o += hh[k] * W2[k * NCLS + t];
    out[r * NCLS + t] = o;
  }
}

// ---------------------------------------------------------------------------
extern "C" void kernel_launch(void* const* d_in, const int* in_sizes, int n_in,
                              void* d_out, int out_size, void* d_ws, size_t ws_size,
                              hipStream_t stream) {
  const float* x[3]    = {(const float*)d_in[0], (const float*)d_in[1], (const float*)d_in[2]};
  const float* encW[3] = {(const float*)d_in[3], (const float*)d_in[4], (const float*)d_in[5]};
  const float* enc_b = (const float*)d_in[6];
  const float* bn_g  = (const float*)d_in[7];
  const float* bn_b  = (const float*)d_in[8];
  const float* gc1W  = (const float*)d_in[9];
  const float* gc1b  = (const float*)d_in[10];
  const float* gc2W  = (const float*)d_in[11];
  const float* gc2b  = (const float*)d_in[12];
  const float* clfW  = (const float*)d_in[13];
  const float* clfb  = (const float*)d_in[14];
  const float* attn  = (const float*)d_in[15];
  const float* f1W   = (const float*)d_in[16];
  const float* f1b   = (const float*)d_in[17];
  const float* f2W   = (const float*)d_in[18];
  const float* f2b   = (const float*)d_in[19];
  float* out = (float*)d_out;

  // Workspace layout
  const size_t NH = (size_t)NROWS * HID;
  float* ws = (float*)d_ws;
  float* FN = ws;                                  // fp32 fn
  float* A  = FN + NH;                             // encoder out (pre-bn)
  float* C  = A + NH;                              // gemm temp
  float* Bf = C + NH;                              // h2 fp32
  int*   nidx = (int*)(Bf + NH);
  float* nval = (float*)(nidx + (size_t)NROWS * TOPK);
  float* dinv = nval + (size_t)NROWS * TOPK;
  float* logits = dinv + NROWS;
  float* fused = logits + (size_t)3 * NROWS * NCLS;
  float* ps    = fused + (size_t)NROWS * NCLS;     // 64*256
  float* ps2   = ps + 64 * HID;
  float* scale = ps2 + 64 * HID;
  float* shift = scale + HID;
  ushort* Ph = (ushort*)(shift + HID);             // hi-limb fn
  ushort* Fh = Ph + NH;                            // gc1 A limbs
  ushort* Fl = Fh + NH;
  ushort* Hh = Fl + NH;                            // gc2 A limbs
  ushort* Hl = Hh + NH;
  ushort* Ah = Hl + NH;                            // encoder A limbs (Kp<=1024)
  ushort* Al = Ah + (size_t)NROWS * 1024;
  ushort* Wh = Al + (size_t)NROWS * 1024;          // B limbs (HID x Kp<=1024)
  ushort* Wl = Wh + (size_t)HID * 1024;
  float* stripe = (float*)(Wl + (size_t)HID * 1024);
  const size_t fixed_bytes = (size_t)((char*)stripe - (char*)ws);
  const size_t avail = (ws_size > fixed_bytes) ? (ws_size - fixed_bytes) : 0;
  int SR = 2048;  // 64 MB stripe -> L3-resident
  while (SR > 256 && (size_t)SR * NROWS * sizeof(float) > avail) SR >>= 1;

  const dim3 blk(256);
  for (int i = 0; i < 3; ++i) {
    const int D = in_sizes[i] / NROWS;
    int Kp = 256, ksh = 8;
    while (Kp < D) { Kp <<= 1; ksh++; }
    // encoder: pack limbs of x and W^T, then A = relu(x @ W + b)
    packAB_kernel<<<((NROWS + HID) << ksh) / 256, blk, 0, stream>>>(
        x[i], encW[i], Ah, Al, Wh, Wl, D, Kp, ksh);
    limbgemm_kernel<true, 1><<<512, blk, 0, stream>>>(Ah, Al, Wh, Wl,
                                                      enc_b + i * HID, A, Kp);
    // coalesced BN + fused rownorm/limb-emit
    bn_stats_kernel<<<64, blk, 0, stream>>>(A, ps, ps2);
    bn_finalize_kernel<<<1, blk, 0, stream>>>(ps, ps2, bn_g + i * HID, bn_b + i * HID,
                                              scale, shift);
    bn_rownorm_kernel<<<NROWS, blk, 0, stream>>>(A, scale, shift, FN, Ph, Fh, Fl);
    // sim stripes (hi-limb MFMA, L3-resident) + per-row top-k (exact refine)
    for (int s0 = 0; s0 < NROWS; s0 += SR) {
      simgemm_kernel<<<dim3(NROWS / TN, SR / TM), blk, 0, stream>>>(Ph, stripe, s0);
      topk_kernel<<<SR / 4, blk, 0, stream>>>(stripe, s0, FN, nidx, nval, dinv);
    }
    // gc1: C = feat @ W1 (limb MFMA), h1 -> limbs via spmm epilogue
    packW_kernel<<<(HID * HID) / 256, blk, 0, stream>>>(gc1W + (size_t)i * HID * HID, Wh, Wl);
    limbgemm_kernel<false, 0><<<512, blk, 0, stream>>>(Fh, Fl, Wh, Wl, nullptr, C, HID);
    spmm_kernel<1><<<NROWS, blk, 0, stream>>>(C, nidx, nval, dinv, gc1b + i * HID,
                                              nullptr, Hh, Hl);
    // gc2
    packW_kernel<<<(HID * HID) / 256, blk, 0, stream>>>(gc2W + (size_t)i * HID * HID, Wh, Wl);
    limbgemm_kernel<false, 0><<<512, blk, 0, stream>>>(Hh, Hl, Wh, Wl, nullptr, C, HID);
    spmm_kernel<0><<<NROWS, blk, 0, stream>>>(C, nidx, nval, dinv, gc2b + i * HID,
                                              Bf, nullptr, nullptr);
    clf_kernel<<<(NROWS * NCLS + 255) / 256, blk, 0, stream>>>(Bf, clfW + (size_t)i * HID * NCLS,
                                                               clfb + i * NCLS,
                                                               logits + (size_t)i * NROWS * NCLS);
  }
  fuse_kernel<<<(NROWS * NCLS + 255) / 256, blk, 0, stream>>>(logits, attn, fused);
  head_kernel<<<NROWS, dim3(128), 0, stream>>>(fused, f1W, f1b, f2W, f2b, out);
}

// Round 8
// 1100.818 us; speedup vs baseline: 2.1699x; 1.1725x over previous
//
#include <hip/hip_runtime.h>
#include <cfloat>
#include <cstdint>
#include <cstddef>

#define NROWS 8192
#define HID 256
#define NCLS 5
#define TOPK 10
#define CAP 256     // per-row candidate capacity (typ. ~20-60 used)
#define TM 128
#define TN 128
#define BK 32

typedef __bf16 bf16x8 __attribute__((ext_vector_type(8)));
typedef float f32x4 __attribute__((ext_vector_type(4)));

__device__ inline ushort f2bf(float x) {
  unsigned u = __float_as_uint(x);
  unsigned r = (u + 0x7fffu + ((u >> 16) & 1u)) >> 16;  // RNE
  return (ushort)r;
}
__device__ inline float bf2f(ushort b) { return __uint_as_float(((unsigned)b) << 16); }

// async global->LDS 16B/lane; LDS dest is wave-uniform base + lane*16
__device__ __forceinline__ void load_lds16(const void* g, void* l) {
  __builtin_amdgcn_global_load_lds(
      (const __attribute__((address_space(1))) void*)g,
      (__attribute__((address_space(3))) void*)l, 16, 0, 0);
}

// ---------------------------------------------------------------------------
// Encoder pack: X rows (M x D fp32 -> hi/lo bf16 limb planes, K padded to Kp)
// and W (D x HID fp32, transposed -> HID x Kp limb planes).
// ---------------------------------------------------------------------------
__global__ __launch_bounds__(256) void packAB_kernel(const float* __restrict__ X,
    const float* __restrict__ W, ushort* __restrict__ Ah, ushort* __restrict__ Al,
    ushort* __restrict__ Bh, ushort* __restrict__ Bl, int D, int Kp, int ksh) {
  const int id = blockIdx.x * 256 + threadIdx.x;
  const int atotal = NROWS << ksh;
  if (id < atotal) {
    const int r = id >> ksh, k = id & (Kp - 1);
    const float x = (k < D) ? X[(size_t)r * D + k] : 0.f;
    const ushort h = f2bf(x);
    Ah[id] = h;
    Al[id] = f2bf(x - bf2f(h));
  } else {
    const int id2 = id - atotal;
    if (id2 < (HID << ksh)) {
      const int n = id2 >> ksh, k = id2 & (Kp - 1);
      const float x = (k < D) ? W[(size_t)k * HID + n] : 0.f;
      const ushort h = f2bf(x);
      Bh[id2] = h;
      Bl[id2] = f2bf(x - bf2f(h));
    }
  }
}

// ---------------------------------------------------------------------------
// GCN weight pack: W [HID x HID] -> transposed limb planes [HID x 256].
// ---------------------------------------------------------------------------
__global__ __launch_bounds__(256) void packW_kernel(const float* __restrict__ W,
    ushort* __restrict__ Bh, ushort* __restrict__ Bl) {
  const int id = blockIdx.x * 256 + threadIdx.x;  // 65536
  const int k = id >> 8, n = id & 255;            // coalesced read over n
  const float x = W[(size_t)k * HID + n];
  const ushort h = f2bf(x);
  Bh[(size_t)n * HID + k] = h;
  Bl[(size_t)n * HID + k] = f2bf(x - bf2f(h));
}

// ---------------------------------------------------------------------------
// 3-segment two-limb bf16 MFMA GEMM: C[NROWS x HID] = act(A @ B^T + bias).
// Segments hh + hl + lh (ll ~2^-18, dropped). 64x64 tile, 4 waves (2x2),
// XCD-swizzled 1-D grid for A-tile L2 reuse.
// ---------------------------------------------------------------------------
template<bool BIAS, int ACT>
__global__ __launch_bounds__(256) void limbgemm_kernel(const ushort* __restrict__ Ah,
    const ushort* __restrict__ Al, const ushort* __restrict__ Bh,
    const ushort* __restrict__ Bl, const float* __restrict__ bias,
    float* __restrict__ C, int Kp) {
  __shared__ ushort AsH[64 * BK], AsL[64 * BK], BsH[64 * BK], BsL[64 * BK];
  const int tid = threadIdx.x;
  const int wave = tid >> 6, lane = tid & 63;
  const int bid = blockIdx.x;
  const int xcd = bid & 7, slot = bid >> 3;
  const int bxi = slot & 3;
  const int byi = xcd * 16 + (slot >> 2);
  const int bm = byi * 64, bn = bxi * 64;
  const int wr = (wave >> 1) * 32, wc = (wave & 1) * 32;

  f32x4 acc[2][2];
  const f32x4 zero = {0.f, 0.f, 0.f, 0.f};
  acc[0][0] = zero; acc[0][1] = zero; acc[1][0] = zero; acc[1][1] = zero;

  const int r0 = tid >> 2, kl0 = (tid & 3) ^ ((r0 & 3) ^ ((r0 >> 2) & 1));
  const size_t aoff = (size_t)(bm + r0) * Kp + kl0 * 8;
  const size_t boff = (size_t)(bn + r0) * Kp + kl0 * 8;

  for (int k0 = 0; k0 < Kp; k0 += BK) {
    __syncthreads();
    load_lds16(Ah + aoff + k0, &AsH[tid * 8]);
    load_lds16(Al + aoff + k0, &AsL[tid * 8]);
    load_lds16(Bh + boff + k0, &BsH[tid * 8]);
    load_lds16(Bl + boff + k0, &BsL[tid * 8]);
    __syncthreads();
    bf16x8 ah[2], al[2], bh[2], bl[2];
    const int kg = lane >> 4;
    #pragma unroll
    for (int f = 0; f < 2; ++f) {
      const int m = wr + f * 16 + (lane & 15);
      const int sa = m * 4 + (kg ^ (m & 3) ^ ((m >> 2) & 1));
      ah[f] = *(const bf16x8*)&AsH[sa * 8];
      al[f] = *(const bf16x8*)&AsL[sa * 8];
      const int n = wc + f * 16 + (lane & 15);
      const int sb = n * 4 + (kg ^ (n & 3) ^ ((n >> 2) & 1));
      bh[f] = *(const bf16x8*)&BsH[sb * 8];
      bl[f] = *(const bf16x8*)&BsL[sb * 8];
    }
    #pragma unroll
    for (int fr = 0; fr < 2; ++fr)
      #pragma unroll
      for (int fc = 0; fc < 2; ++fc) {
        acc[fr][fc] = __builtin_amdgcn_mfma_f32_16x16x32_bf16(ah[fr], bh[fc], acc[fr][fc], 0, 0, 0);
        acc[fr][fc] = __builtin_amdgcn_mfma_f32_16x16x32_bf16(ah[fr], bl[fc], acc[fr][fc], 0, 0, 0);
        acc[fr][fc] = __builtin_amdgcn_mfma_f32_16x16x32_bf16(al[fr], bh[fc], acc[fr][fc], 0, 0, 0);
      }
  }
  const int cq = lane >> 4, cc = lane & 15;
  #pragma unroll
  for (int fr = 0; fr < 2; ++fr) {
    #pragma unroll
    for (int fc = 0; fc < 2; ++fc) {
      const int rb = bm + wr + fr * 16 + cq * 4;
      const int col = bn + wc + fc * 16 + cc;
      const float bb = BIAS ? bias[col] : 0.f;
      float* cp = C + (size_t)rb * HID + col;
      #pragma unroll
      for (int e = 0; e < 4; ++e) {
        float v = acc[fr][fc][e] + bb;
        if (ACT == 1) v = fmaxf(v, 0.f);
        cp[(size_t)e * HID] = v;
      }
    }
  }
}

// ---------------------------------------------------------------------------
// Coalesced BatchNorm, 3 stages.
// ---------------------------------------------------------------------------
__global__ __launch_bounds__(256) void bn_stats_kernel(const float* __restrict__ F,
    float* __restrict__ ps, float* __restrict__ ps2) {
  const int b = blockIdx.x, t = threadIdx.x;
  float s = 0.f, s2 = 0.f;
  const float* p = F + (size_t)b * 128 * HID + t;
  for (int r = 0; r < 128; ++r) {
    const float v = p[(size_t)r * HID];
    s += v; s2 += v * v;
  }
  ps[b * HID + t] = s;
  ps2[b * HID + t] = s2;
}

__global__ __launch_bounds__(256) void bn_finalize_kernel(const float* __restrict__ ps,
    const float* __restrict__ ps2, const float* __restrict__ g,
    const float* __restrict__ b, float* __restrict__ scale, float* __restrict__ shift) {
  const int t = threadIdx.x;
  float s = 0.f, s2 = 0.f;
  for (int i = 0; i < 64; ++i) { s += ps[i * HID + t]; s2 += ps2[i * HID + t]; }
  const float mu = s / (float)NROWS;
  const float var = s2 / (float)NROWS - mu * mu;
  const float rstd = rsqrtf(var + 1e-5f);
  const float sc = rstd * g[t];
  scale[t] = sc;
  shift[t] = b[t] - mu * sc;
}

// ---------------------------------------------------------------------------
// Fused bn-apply + L2 rownorm. Emits FN (fp32 fn), Ph (hi-limb fn),
// Fh/Fl (two-limb bn'd feat for gc1).
// ---------------------------------------------------------------------------
__global__ __launch_bounds__(256) void bn_rownorm_kernel(const float* __restrict__ F,
    const float* __restrict__ scale, const float* __restrict__ shift,
    float* __restrict__ FN, ushort* __restrict__ Ph,
    ushort* __restrict__ Fh, ushort* __restrict__ Fl) {
  const int r = blockIdx.x, t = threadIdx.x;
  const float f = F[(size_t)r * HID + t] * scale[t] + shift[t];
  __shared__ float sh[256];
  sh[t] = f * f;
  __syncthreads();
  for (int st = 128; st > 0; st >>= 1) {
    if (t < st) sh[t] += sh[t + st];
    __syncthreads();
  }
  const float inv = 1.0f / fmaxf(sqrtf(sh[0]), 1e-12f);
  const float fn = f * inv;
  const size_t o = (size_t)r * HID + t;
  FN[o] = fn;
  Ph[o] = f2bf(fn);
  const ushort h = f2bf(f);
  Fh[o] = h;
  Fl[o] = f2bf(f - bf2f(h));
}

// ---------------------------------------------------------------------------
// Stripe-free sim: 128x128 tiles of Ph @ Ph^T (K=256 hi-limb MFMA).
// PASS 0: epilogue reduces tile to per-row tile-max (self-excluded) -> M.
// PASS 1: recompute tile; lanes append register values >= tau[row] to the
//         per-row global candidate list (device atomics; ~30 hits/row total).
// Sim values never touch HBM.
// ---------------------------------------------------------------------------
template<int PASS>
__global__ __launch_bounds__(256) void simtile_kernel(const ushort* __restrict__ P,
    float* __restrict__ M, const float* __restrict__ tauv,
    int* __restrict__ gcnt, int* __restrict__ gidx) {
  __shared__ ushort As[TM * BK];
  __shared__ ushort Bs[TN * BK];
  const int tid = threadIdx.x;
  const int wave = tid >> 6, lane = tid & 63;
  const int bm = blockIdx.y * TM;
  const int bn = blockIdx.x * TN;
  const int wr = (wave >> 1) * 64;
  const int wc = (wave & 1) * 64;

  f32x4 acc[4][4];
  const f32x4 zero = {0.f, 0.f, 0.f, 0.f};
  #pragma unroll
  for (int i = 0; i < 4; ++i)
    #pragma unroll
    for (int j = 0; j < 4; ++j) acc[i][j] = zero;

  const int p0 = tid, p1 = tid + 256;
  const int r0 = p0 >> 2, kl0 = (p0 & 3) ^ ((r0 & 3) ^ ((r0 >> 2) & 1));
  const int r1 = p1 >> 2, kl1 = (p1 & 3) ^ ((r1 & 3) ^ ((r1 >> 2) & 1));
  const ushort* pa0 = P + (size_t)(bm + r0) * HID + kl0 * 8;
  const ushort* pa1 = P + (size_t)(bm + r1) * HID + kl1 * 8;
  const ushort* pb0 = P + (size_t)(bn + r0) * HID + kl0 * 8;
  const ushort* pb1 = P + (size_t)(bn + r1) * HID + kl1 * 8;

  for (int k0 = 0; k0 < HID; k0 += BK) {
    __syncthreads();
    load_lds16(pa0 + k0, &As[p0 * 8]);
    load_lds16(pa1 + k0, &As[p1 * 8]);
    load_lds16(pb0 + k0, &Bs[p0 * 8]);
    load_lds16(pb1 + k0, &Bs[p1 * 8]);
    __syncthreads();
    bf16x8 af[4], bf[4];
    const int kg = lane >> 4;
    #pragma unroll
    for (int f = 0; f < 4; ++f) {
      const int m = wr + f * 16 + (lane & 15);
      const int sa = m * 4 + (kg ^ (m & 3) ^ ((m >> 2) & 1));
      af[f] = *(const bf16x8*)&As[sa * 8];
      const int n = wc + f * 16 + (lane & 15);
      const int sb = n * 4 + (kg ^ (n & 3) ^ ((n >> 2) & 1));
      bf[f] = *(const bf16x8*)&Bs[sb * 8];
    }
    #pragma unroll
    for (int fr = 0; fr < 4; ++fr)
      #pragma unroll
      for (int fc = 0; fc < 4; ++fc)
        acc[fr][fc] = __builtin_amdgcn_mfma_f32_16x16x32_bf16(af[fr], bf[fc], acc[fr][fc], 0, 0, 0);
  }
  const int cq = lane >> 4, cc = lane & 15;
  if (PASS == 0) {
    __shared__ float Ml[2][TM];
    #pragma unroll
    for (int fr = 0; fr < 4; ++fr) {
      #pragma unroll
      for (int e = 0; e < 4; ++e) {
        const int lrow = wr + fr * 16 + cq * 4 + e;
        const int grow = bm + lrow;
        float mx = -FLT_MAX;
        #pragma unroll
        for (int fc = 0; fc < 4; ++fc) {
          const int col = bn + wc + fc * 16 + cc;
          mx = fmaxf(mx, (col == grow) ? -FLT_MAX : acc[fr][fc][e]);
        }
        #pragma unroll
        for (int s = 1; s < 16; s <<= 1) mx = fmaxf(mx, __shfl_xor(mx, s));
        if (cc == 0) Ml[wave & 1][lrow] = mx;
      }
    }
    __syncthreads();
    if (tid < TM) M[(size_t)(bm + tid) * 64 + blockIdx.x] = fmaxf(Ml[0][tid], Ml[1][tid]);
  } else {
    __shared__ float taul[TM];
    if (tid < TM) taul[tid] = tauv[bm + tid];
    __syncthreads();
    #pragma unroll
    for (int fr = 0; fr < 4; ++fr) {
      #pragma unroll
      for (int e = 0; e < 4; ++e) {
        const int lrow = wr + fr * 16 + cq * 4 + e;
        const int grow = bm + lrow;
        const float t = taul[lrow];
        #pragma unroll
        for (int fc = 0; fc < 4; ++fc) {
          const int col = bn + wc + fc * 16 + cc;
          const float v = acc[fr][fc][e];
          if (col != grow && v >= t) {
            const int pos = atomicAdd(&gcnt[grow], 1);
            if (pos < CAP) gidx[(size_t)grow * CAP + pos] = col;
          }
        }
      }
    }
  }
}

// ---------------------------------------------------------------------------
// tau[row] = 16th largest of the 64 tile-maxes (valid top-16 lower bound:
// the top-16 tiles' maxes are 16 distinct non-self elements >= tau).
// Also zeroes gcnt (ws is re-poisoned before every launch).
// ---------------------------------------------------------------------------
__global__ __launch_bounds__(256) void tau_kernel(const float* __restrict__ M,
    float* __restrict__ tauv, int* __restrict__ gcnt) {
  const int wave = threadIdx.x >> 6, lane = threadIdx.x & 63;
  const int row = blockIdx.x * 4 + wave;
  float cur = M[(size_t)row * 64 + lane];
  float tau = cur;
  #pragma unroll
  for (int sel = 0; sel < 16; ++sel) {
    float bv = cur;
    int bl = lane;
    #pragma unroll
    for (int s = 1; s < 64; s <<= 1) {
      const float ov = __shfl_xor(bv, s);
      const int ol = __shfl_xor(bl, s);
      if (ov > bv || (ov == bv && ol < bl)) { bv = ov; bl = ol; }
    }
    tau = bv;
    if (lane == bl) cur = -FLT_MAX;
  }
  if (lane == 0) { tauv[row] = tau; gcnt[row] = 0; }
}

// ---------------------------------------------------------------------------
// Exact refinement: fp32 dots for all candidates, exact top-10, L1-normalize.
// One wave per row.
// ---------------------------------------------------------------------------
__global__ __launch_bounds__(256) void refine_kernel(const int* __restrict__ gcnt,
    const int* __restrict__ gidx, const float* __restrict__ FN,
    int* __restrict__ nidx, float* __restrict__ nval, float* __restrict__ dinv) {
  const int wave = threadIdx.x >> 6, lane = threadIdx.x & 63;
  const int row = blockIdx.x * 4 + wave;
  const int cnt = min(gcnt[row], CAP);
  __shared__ float fnrow[4][HID];
  __shared__ float ev[4][CAP];
  ((float4*)fnrow[wave])[lane] = ((const float4*)(FN + (size_t)row * HID))[lane];
  __syncthreads();
  const int c = lane >> 2, q4 = lane & 3;
  for (int b0 = 0; b0 < cnt; b0 += 16) {
    const int ci = b0 + c;
    const int cand = (ci < cnt) ? gidx[(size_t)row * CAP + ci] : 0;
    float s = 0.f;
    const float* fc = FN + (size_t)cand * HID + q4 * 64;
    const float* fr = fnrow[wave] + q4 * 64;
    #pragma unroll 8
    for (int k = 0; k < 64; ++k) s += fr[k] * fc[k];
    s += __shfl_xor(s, 1);
    s += __shfl_xor(s, 2);
    if (q4 == 0 && ci < cnt) ev[wave][ci] = s;
  }
  __syncthreads();
  float outv[TOPK];
  int outi[TOPK];
  float sum = 1.0f;  // diag contributes 1
  #pragma unroll
  for (int sel = 0; sel < TOPK; ++sel) {
    float bv = -FLT_MAX;
    int bp = 0;
    #pragma unroll
    for (int j = 0; j < 4; ++j) {
      const int p = lane + j * 64;
      if (p < cnt) {
        const float v = ev[wave][p];
        if (v > bv) { bv = v; bp = p; }
      }
    }
    #pragma unroll
    for (int s = 1; s < 64; s <<= 1) {
      const float ov = __shfl_xor(bv, s);
      const int op = __shfl_xor(bp, s);
      if (ov > bv || (ov == bv && op < bp)) { bv = ov; bp = op; }
    }
    outv[sel] = bv;
    outi[sel] = bp;
    sum += fabsf(bv);
    if (lane == 0) ev[wave][bp] = -FLT_MAX;
  }
  if (lane == 0) {
    const float inv = 1.0f / fmaxf(sum, 1e-12f);
    dinv[row] = inv;
    #pragma unroll
    for (int sel = 0; sel < TOPK; ++sel) {
      nval[row * TOPK + sel] = outv[sel] * inv;
      nidx[row * TOPK + sel] = gidx[(size_t)row * CAP + outi[sel]];
    }
  }
}

// ---------------------------------------------------------------------------
// Sparse adj (11 nnz/row) @ T + bias, leaky_relu(0.25).
// EMIT=0: write fp32 H. EMIT=1: write two-limb bf16 planes (next gemm's A).
// ---------------------------------------------------------------------------
template<int EMIT>
__global__ __launch_bounds__(256) void spmm_kernel(const float* __restrict__ T,
    const int* __restrict__ nidx, const float* __restrict__ nval,
    const float* __restrict__ dinv, const float* __restrict__ bias,
    float* __restrict__ H, ushort* __restrict__ Hh, ushort* __restrict__ Hl) {
  const int r = blockIdx.x, c = threadIdx.x;
  float acc = dinv[r] * T[(size_t)r * HID + c];
  #pragma unroll
  for (int n = 0; n < TOPK; ++n) {
    acc += nval[r * TOPK + n] * T[(size_t)nidx[r * TOPK + n] * HID + c];
  }
  acc += bias[c];
  const float v = acc >= 0.f ? acc : 0.25f * acc;
  const size_t o = (size_t)r * HID + c;
  if (EMIT == 0) {
    H[o] = v;
  } else {
    const ushort h = f2bf(v);
    Hh[o] = h;
    Hl[o] = f2bf(v - bf2f(h));
  }
}

__global__ __launch_bounds__(256) void clf_kernel(const float* __restrict__ H,
    const float* __restrict__ W, const float* __restrict__ b,
    float* __restrict__ L) {
  const int id = blockIdx.x * 256 + threadIdx.x;
  if (id >= NROWS * NCLS) return;
  const int r = id / NCLS, c = id % NCLS;
  float s = b[c];
  const float* hr = H + (size_t)r * HID;
  for (int k = 0; k < HID; ++k) s += hr[k] * W[k * NCLS + c];
  L[id] = s;
}

__global__ __launch_bounds__(256) void fuse_kernel(const float* __restrict__ L,
    const float* __restrict__ attn, float* __restrict__ fused) {
  const int id = blockIdx.x * 256 + threadIdx.x;
  if (id >= NROWS * NCLS) return;
  const float a0 = attn[0], a1 = attn[1], a2 = attn[2];
  const float m = fmaxf(a0, fmaxf(a1, a2));
  const float e0 = expf(a0 - m), e1 = expf(a1 - m), e2 = expf(a2 - m);
  const float inv = 1.0f / (e0 + e1 + e2);
  const float l0 = L[id];
  const float l1 = L[NROWS * NCLS + id];
  const float l2 = L[2 * NROWS * NCLS + id];
  const float s0 = 1.0f / (1.0f + expf(-l0));
  const float s1 = 1.0f / (1.0f + expf(-l1));
  const float s2 = 1.0f / (1.0f + expf(-l2));
  fused[id] = (e0 * s0 + e1 * s1 + e2 * s2) * inv;
}

__global__ __launch_bounds__(128) void head_kernel(const float* __restrict__ fused,
    const float* __restrict__ W1, const float* __restrict__ b1,
    const float* __restrict__ W2, const float* __restrict__ b2,
    float* __restrict__ out) {
  const int r = blockIdx.x, t = threadIdx.x;
  __shared__ float f[NCLS];
  __shared__ float hh[128];
  if (t < NCLS) f[t] = fused[r * NCLS + t];
  __syncthreads();
  float s = b1[t];
  #pragma unroll
  for (int k = 0; k < NCLS; ++k) s += f[k] * W1[k * 128 + t];
  hh[t] = s >= 0.f ? s : 0.25f * s;
  __syncthreads();
  if (t < NCLS) {
    float o = b2[t];
    for (int k = 0; k < 128; ++k) o += hh[k] * W2[k * NCLS + t];
    out[r * NCLS + t] = o;
  }
}

// ---------------------------------------------------------------------------
extern "C" void kernel_launch(void* const* d_in, const int* in_sizes, int n_in,
                              void* d_out, int out_size, void* d_ws, size_t ws_size,
                              hipStream_t stream) {
  const float* x[3]    = {(const float*)d_in[0], (const float*)d_in[1], (const float*)d_in[2]};
  const float* encW[3] = {(const float*)d_in[3], (const float*)d_in[4], (const float*)d_in[5]};
  const float* enc_b = (const float*)d_in[6];
  const float* bn_g  = (const float*)d_in[7];
  const float* bn_b  = (const float*)d_in[8];
  const float* gc1W  = (const float*)d_in[9];
  const float* gc1b  = (const float*)d_in[10];
  const float* gc2W  = (const float*)d_in[11];
  const float* gc2b  = (const float*)d_in[12];
  const float* clfW  = (const float*)d_in[13];
  const float* clfb  = (const float*)d_in[14];
  const float* attn  = (const float*)d_in[15];
  const float* f1W   = (const float*)d_in[16];
  const float* f1b   = (const float*)d_in[17];
  const float* f2W   = (const float*)d_in[18];
  const float* f2b   = (const float*)d_in[19];
  float* out = (float*)d_out;

  // Workspace layout
  const size_t NH = (size_t)NROWS * HID;
  float* ws = (float*)d_ws;
  float* FN = ws;                                  // fp32 fn
  float* A  = FN + NH;                             // encoder out (pre-bn)
  float* C  = A + NH;                              // gemm temp
  float* Bf = C + NH;                              // h2 fp32
  int*   nidx = (int*)(Bf + NH);
  float* nval = (float*)(nidx + (size_t)NROWS * TOPK);
  float* dinv = nval + (size_t)NROWS * TOPK;
  float* logits = dinv + NROWS;
  float* fused = logits + (size_t)3 * NROWS * NCLS;
  float* ps    = fused + (size_t)NROWS * NCLS;     // 64*256
  float* ps2   = ps + 64 * HID;
  float* scale = ps2 + 64 * HID;
  float* shift = scale + HID;
  float* M     = shift + HID;                      // 8192*64 tile maxes
  float* tauv  = M + (size_t)NROWS * 64;           // 8192
  int*   gcnt  = (int*)(tauv + NROWS);             // 8192
  int*   gidx  = gcnt + NROWS;                     // 8192*CAP
  ushort* Ph = (ushort*)(gidx + (size_t)NROWS * CAP);  // hi-limb fn
  ushort* Fh = Ph + NH;                            // gc1 A limbs
  ushort* Fl = Fh + NH;
  ushort* Hh = Fl + NH;                            // gc2 A limbs
  ushort* Hl = Hh + NH;
  ushort* Ah = Hl + NH;                            // encoder A limbs (Kp<=1024)
  ushort* Al = Ah + (size_t)NROWS * 1024;
  ushort* Wh = Al + (size_t)NROWS * 1024;          // B limbs (HID x Kp<=1024)
  ushort* Wl = Wh + (size_t)HID * 1024;

  const dim3 blk(256);
  for (int i = 0; i < 3; ++i) {
    const int D = in_sizes[i] / NROWS;
    int Kp = 256, ksh = 8;
    while (Kp < D) { Kp <<= 1; ksh++; }
    // encoder: pack limbs of x and W^T, then A = relu(x @ W + b)
    packAB_kernel<<<((NROWS + HID) << ksh) / 256, blk, 0, stream>>>(
        x[i], encW[i], Ah, Al, Wh, Wl, D, Kp, ksh);
    limbgemm_kernel<true, 1><<<512, blk, 0, stream>>>(Ah, Al, Wh, Wl,
                                                      enc_b + i * HID, A, Kp);
    // coalesced BN + fused rownorm/limb-emit
    bn_stats_kernel<<<64, blk, 0, stream>>>(A, ps, ps2);
    bn_finalize_kernel<<<1, blk, 0, stream>>>(ps, ps2, bn_g + i * HID, bn_b + i * HID,
                                              scale, shift);
    bn_rownorm_kernel<<<NROWS, blk, 0, stream>>>(A, scale, shift, FN, Ph, Fh, Fl);
    // stripe-free knn graph: tile-max pass -> tau -> compaction pass -> refine
    simtile_kernel<0><<<dim3(64, 64), blk, 0, stream>>>(Ph, M, nullptr, nullptr, nullptr);
    tau_kernel<<<NROWS / 4, blk, 0, stream>>>(M, tauv, gcnt);
    simtile_kernel<1><<<dim3(64, 64), blk, 0, stream>>>(Ph, nullptr, tauv, gcnt, gidx);
    refine_kernel<<<NROWS / 4, blk, 0, stream>>>(gcnt, gidx, FN, nidx, nval, dinv);
    // gc1: C = feat @ W1 (limb MFMA), h1 -> limbs via spmm epilogue
    packW_kernel<<<(HID * HID) / 256, blk, 0, stream>>>(gc1W + (size_t)i * HID * HID, Wh, Wl);
    limbgemm_kernel<false, 0><<<512, blk, 0, stream>>>(Fh, Fl, Wh, Wl, nullptr, C, HID);
    spmm_kernel<1><<<NROWS, blk, 0, stream>>>(C, nidx, nval, dinv, gc1b + i * HID,
                                              nullptr, Hh, Hl);
    // gc2
    packW_kernel<<<(HID * HID) / 256, blk, 0, stream>>>(gc2W + (size_t)i * HID * HID, Wh, Wl);
    limbgemm_kernel<false, 0><<<512, blk, 0, stream>>>(Hh, Hl, Wh, Wl, nullptr, C, HID);
    spmm_kernel<0><<<NROWS, blk, 0, stream>>>(C, nidx, nval, dinv, gc2b + i * HID,
                                              Bf, nullptr, nullptr);
    clf_kernel<<<(NROWS * NCLS + 255) / 256, blk, 0, stream>>>(Bf, clfW + (size_t)i * HID * NCLS,
                                                               clfb + i * NCLS,
                                                               logits + (size_t)i * NROWS * NCLS);
  }
  fuse_kernel<<<(NROWS * NCLS + 255) / 256, blk, 0, stream>>>(logits, attn, fused);
  head_kernel<<<NROWS, dim3(128), 0, stream>>>(fused, f1W, f1b, f2W, f2b, out);
}